// Round 3
// baseline (342.884 us; speedup 1.0000x reference)
//
#include <hip/hip_runtime.h>

// ---------------------------------------------------------------------------
// MSAAttention fused pipeline (MI355X / gfx950), bf16 MFMA throughout.
//
// out = concat[softmax(qk^T*s)v @ w_merge + b_merge, ib] @ w_proj + b_proj
// Folded: wcombT holds (w_merge@w_proj_top)^T and w_proj_bot^T — the merge
// GEMM is deleted; biasc = b_merge@w_proj_top + b_proj.
// SCALE*log2e folded into q; softmax in exp2 domain, no max-subtraction.
// attn: 512-thread blocks (8 waves = q-half x kv-quarter) -> 16 waves/CU =
// 4 waves/SIMD for latency hiding (R2 was 2/SIMD and ~2/3 stall-bound).
// 32x32x16 MFMA, swapped QK^T (S^T = K·Q^T), P fully in-register
// (v_cvt_pk_bf16_f32 + v_permlane32_swap_b32). K/V frags reused across 2
// q-groups. 2-round cross-wave kv combine at the end. Double-buffered K/V,
// 1 barrier/iter, setprio around MFMA clusters.
// ---------------------------------------------------------------------------

typedef unsigned short u16;
typedef unsigned int u32;
typedef __bf16 bf16x8 __attribute__((ext_vector_type(8)));
typedef u16 su16x8 __attribute__((ext_vector_type(8)));
typedef u16 su16x4 __attribute__((ext_vector_type(4)));
typedef u32 u32x4 __attribute__((ext_vector_type(4)));
typedef float f32x4 __attribute__((ext_vector_type(4)));
typedef float f32x16 __attribute__((ext_vector_type(16)));

__device__ __forceinline__ u16 f2bf(float f) {
  union { __bf16 h; u16 u; } v;
  v.h = (__bf16)f;
  return v.u;
}

__device__ __forceinline__ float fexp2(float x) {
#if __has_builtin(__builtin_amdgcn_exp2f)
  return __builtin_amdgcn_exp2f(x);
#else
  return __expf(x * 0.6931471805599453f);
#endif
}

__device__ __forceinline__ f32x4 zero4() {
  f32x4 v = {0.f, 0.f, 0.f, 0.f};
  return v;
}

__device__ __forceinline__ f32x4 mfma16(bf16x8 a, bf16x8 b, f32x4 c) {
  return __builtin_amdgcn_mfma_f32_16x16x32_bf16(a, b, c, 0, 0, 0);
}

__device__ __forceinline__ f32x16 mfma32(bf16x8 a, bf16x8 b, f32x16 c) {
  return __builtin_amdgcn_mfma_f32_32x32x16_bf16(a, b, c, 0, 0, 0);
}

// pack two f32 -> one u32 of two bf16 (lo = a, hi = b)
__device__ __forceinline__ u32 pkbf(float a, float b) {
  u32 r;
  asm("v_cvt_pk_bf16_f32 %0, %1, %2" : "=v"(r) : "v"(a), "v"(b));
  return r;
}

// exchange a's hi-lanes with b's lo-lanes
__device__ __forceinline__ void swap32(u32& a, u32& b) {
  asm("v_permlane32_swap_b32 %0, %1" : "+v"(a), "+v"(b));
}

__device__ __forceinline__ bf16x8 mkfrag(u32 w0, u32 w1, u32 w2, u32 w3) {
  union { u32 u[4]; bf16x8 v; } x;
  x.u[0] = w0; x.u[1] = w1; x.u[2] = w2; x.u[3] = w3;
  return x.v;
}

// ---------------------------------------------------------------------------
// prep_ib_kernel (800 blocks): prep paths (0..287) + ib paths (288..799).
// ---------------------------------------------------------------------------
__global__ __launch_bounds__(256) void prep_ib_kernel(
    const float* __restrict__ w_qkv, const float* __restrict__ w_merge,
    const float* __restrict__ w_proj, const float* __restrict__ b_merge,
    const float* __restrict__ b_proj, u16* __restrict__ wqkvT,
    u16* __restrict__ wptT, u16* __restrict__ wcombT, u16* __restrict__ wmb,
    float* __restrict__ biasc, const float* __restrict__ x,
    const float* __restrict__ w_in, const float* __restrict__ b_in,
    const float* __restrict__ w_out, const float* __restrict__ b_out,
    u16* __restrict__ xb, u16* __restrict__ catb) {
  __shared__ __align__(16) char smem[35456];
  int blk = blockIdx.x, tid = threadIdx.x;
  if (blk < 192) {
    const float* src;
    int lsrc, ldd, r0, c0;
    u16* dst;
    if (blk < 96) {
      src = w_qkv; lsrc = 1536; dst = wqkvT; ldd = 256;
      r0 = (blk & 3) * 64; c0 = (blk >> 2) * 64;
    } else if (blk < 160) {
      int b2 = blk - 96;
      src = w_proj; lsrc = 512; dst = wptT; ldd = 512;
      r0 = (b2 & 7) * 64; c0 = (b2 >> 3) * 64;
    } else {
      int b2 = blk - 160;
      src = w_proj + 512 * 512; lsrc = 512; dst = wcombT + 512; ldd = 768;
      r0 = (b2 & 3) * 64; c0 = (b2 >> 2) * 64;
    }
    u16* Ts = (u16*)smem;  // [64][68]
    int rr = tid >> 4, cc4 = (tid & 15) * 4;
#pragma unroll
    for (int rep = 0; rep < 4; ++rep) {
      int r = rr + rep * 16;
      float4 v = *(const float4*)&src[(size_t)(r0 + r) * lsrc + c0 + cc4];
      su16x4 pk = {f2bf(v.x), f2bf(v.y), f2bf(v.z), f2bf(v.w)};
      *(su16x4*)&Ts[r * 68 + cc4] = pk;
    }
    __syncthreads();
    int c = tid & 63, seg = tid >> 6;
    u16 tmp[16];
#pragma unroll
    for (int k = 0; k < 16; ++k) tmp[k] = Ts[(seg * 16 + k) * 68 + c];
    *(su16x8*)&dst[(size_t)(c0 + c) * ldd + r0 + seg * 16] = *(su16x8*)tmp;
    *(su16x8*)&dst[(size_t)(c0 + c) * ldd + r0 + seg * 16 + 8] =
        *(su16x8*)(tmp + 8);
  } else if (blk < 256) {
    int b2 = blk - 192;
#pragma unroll
    for (int rep = 0; rep < 4; ++rep) {
      int i = b2 * 4096 + rep * 1024 + tid * 4;
      float4 v = *(const float4*)&w_merge[i];
      su16x4 pk = {f2bf(v.x), f2bf(v.y), f2bf(v.z), f2bf(v.w)};
      *(su16x4*)&wmb[i] = pk;
    }
  } else if (blk < 288) {
    int col0 = (blk - 256) * 16;
    float(*red)[17] = (float(*)[17])smem;
    int kr = tid >> 4, cc = tid & 15;
    float s = 0.f;
#pragma unroll 4
    for (int j = 0; j < 32; ++j) {
      int k = kr + j * 16;
      s += b_merge[k] * w_proj[(size_t)k * 512 + col0 + cc];
    }
    red[kr][cc] = s;
    __syncthreads();
    if (kr == 0) {
      float a = b_proj[col0 + cc];
#pragma unroll
      for (int t = 0; t < 16; ++t) a += red[t][cc];
      biasc[col0 + cc] = a;
    }
  } else {
    int ib = blk - 288;
    float* wi = (float*)smem;            // 256
    float* wo = (float*)(smem + 1024);   // 256
    float* bi = (float*)(smem + 2048);   // 16
    float* bo = (float*)(smem + 2112);   // 16
    float(*xs)[260] = (float(*)[260])(smem + 2176);
    float(*hs)[260] = (float(*)[260])(smem + 18816);
    wi[tid] = w_in[tid];
    wo[tid] = w_out[tid];
    if (tid < 16) { bi[tid] = b_in[tid]; bo[tid] = b_out[tid]; }
    size_t blkoff = (size_t)ib * 4096;
#pragma unroll
    for (int i = 0; i < 4; ++i) {
      int f = (tid + i * 256) * 4;
      float4 v = *(const float4*)&x[blkoff + f];
      int tok = f >> 8, p = f & 255;
      *(float4*)&xs[tok][p] = v;
      su16x4 pk = {f2bf(v.x), f2bf(v.y), f2bf(v.z), f2bf(v.w)};
      *(su16x4*)&xb[blkoff + f] = pk;
    }
    __syncthreads();
    int t = tid >> 4, p2 = tid & 15;
#pragma unroll
    for (int p1 = 0; p1 < 16; ++p1) {
      float a = bi[p2];
#pragma unroll
      for (int k = 0; k < 16; ++k) a += xs[t][p1 * 16 + k] * wi[k * 16 + p2];
      hs[t][p1 * 16 + p2] = a / (1.f + __expf(-a));
    }
    __syncthreads();
    size_t tok = (size_t)ib * 16 + t;
#pragma unroll
    for (int p1 = 0; p1 < 16; ++p1) {
      float o = bo[p2];
#pragma unroll
      for (int j = 0; j < 16; ++j) o += hs[t][p1 * 16 + j] * wo[j * 16 + p2];
      catb[tok * 768 + 512 + p1 * 16 + p2] = f2bf(o);
    }
  }
}

// ---------------------------------------------------------------------------
// gemm_bt: C[TM-tile][TN-tile] = A[m][k] @ BT[n][k]^T  (both row-major, k-inner)
// OUTMODE 0: f32 out (+bias). 1: bf16 out via LDS-staged b128 stores (+bias,
// scaleQ multiplies cols<512 by SCALE*log2e). 2: bf16 scatter (small tiles).
// ---------------------------------------------------------------------------
template <int TM, int TN, int WGM, int WGN, int OUTMODE>
__global__ __launch_bounds__(256) void gemm_bt(
    const u16* __restrict__ A, int lda, const u16* __restrict__ BT, int ldb,
    int kcount, const float* __restrict__ bias, void* __restrict__ Co, int ldc,
    int scaleQ) {
  constexpr int NROWS = TM + TN;
  constexpr int NLD = NROWS / 64;
  constexpr int MT = TM / WGM / 16;
  constexpr int NT = TN / WGN / 16;
  __shared__ __align__(16) u16 S[NROWS * 40];
  int tid = threadIdx.x;
  int lane = tid & 63, wave = tid >> 6;
  int c = lane & 15, g4 = lane >> 4;
  int m0 = blockIdx.y * TM, n0 = blockIdx.x * TN;
  int wm = (wave / WGN) * (TM / WGM), wn = (wave % WGN) * (TN / WGN);
  f32x4 acc[MT][NT];
#pragma unroll
  for (int a = 0; a < MT; ++a)
#pragma unroll
    for (int b = 0; b < NT; ++b) acc[a][b] = zero4();

  su16x8 pre[NLD];
#pragma unroll
  for (int t = 0; t < NLD; ++t) {
    int gsl = t * 256 + tid;
    int row = gsl >> 2, kg = gsl & 3;
    const u16* p = row < TM ? &A[(size_t)(m0 + row) * lda + kg * 8]
                            : &BT[(size_t)(n0 + row - TM) * ldb + kg * 8];
    pre[t] = *(const su16x8*)p;
  }

  for (int kb = 0; kb < kcount; kb += 32) {
    __syncthreads();
#pragma unroll
    for (int t = 0; t < NLD; ++t) {
      int gsl = t * 256 + tid;
      int row = gsl >> 2, kg = gsl & 3;
      *(su16x8*)&S[row * 40 + kg * 8] = pre[t];
    }
    __syncthreads();
    if (kb + 32 < kcount) {
#pragma unroll
      for (int t = 0; t < NLD; ++t) {
        int gsl = t * 256 + tid;
        int row = gsl >> 2, kg = gsl & 3;
        const u16* p =
            row < TM ? &A[(size_t)(m0 + row) * lda + kb + 32 + kg * 8]
                     : &BT[(size_t)(n0 + row - TM) * ldb + kb + 32 + kg * 8];
        pre[t] = *(const su16x8*)p;
      }
    }
    bf16x8 af[MT], bf[NT];
#pragma unroll
    for (int mt = 0; mt < MT; ++mt)
      af[mt] = *(const bf16x8*)&S[(wm + mt * 16 + c) * 40 + g4 * 8];
#pragma unroll
    for (int nt = 0; nt < NT; ++nt)
      bf[nt] = *(const bf16x8*)&S[(TM + wn + nt * 16 + c) * 40 + g4 * 8];
#pragma unroll
    for (int mt = 0; mt < MT; ++mt)
#pragma unroll
      for (int nt = 0; nt < NT; ++nt)
        acc[mt][nt] = mfma16(af[mt], bf[nt], acc[mt][nt]);
  }

  if (OUTMODE == 0) {
    float* Cf = (float*)Co;
#pragma unroll
    for (int nt = 0; nt < NT; ++nt) {
      int col = n0 + wn + nt * 16 + c;
      float bv = bias ? bias[col] : 0.f;
#pragma unroll
      for (int mt = 0; mt < MT; ++mt)
#pragma unroll
        for (int i = 0; i < 4; ++i)
          Cf[(size_t)(m0 + wm + mt * 16 + g4 * 4 + i) * ldc + col] =
              acc[mt][nt][i] + bv;
    }
  } else if (OUTMODE == 2) {
    u16* C16 = (u16*)Co;
#pragma unroll
    for (int nt = 0; nt < NT; ++nt)
#pragma unroll
      for (int mt = 0; mt < MT; ++mt)
#pragma unroll
        for (int i = 0; i < 4; ++i)
          C16[(size_t)(m0 + wm + mt * 16 + g4 * 4 + i) * ldc + n0 + wn +
              nt * 16 + c] = f2bf(acc[mt][nt][i]);
  } else {
    // OUTMODE 1: requires TM==128, TN==128, WGM==2
    u16* C16 = (u16*)Co;
    u16* Cs = S;  // [64][136] per half
    __syncthreads();
#pragma unroll
    for (int half = 0; half < 2; ++half) {
      if ((wave >> 1) == half) {
#pragma unroll
        for (int nt = 0; nt < NT; ++nt) {
          int col = n0 + wn + nt * 16 + c;
          float bv = bias ? bias[col] : 0.f;
          float sc = (scaleQ && col < 512) ? 0.18033688011112042f : 1.f;
#pragma unroll
          for (int mt = 0; mt < MT; ++mt)
#pragma unroll
            for (int i = 0; i < 4; ++i)
              Cs[(mt * 16 + g4 * 4 + i) * 136 + wn + nt * 16 + c] =
                  f2bf((acc[mt][nt][i] + bv) * sc);
        }
      }
      __syncthreads();
      {
        int row = tid >> 2;
#pragma unroll
        for (int t = 0; t < 4; ++t) {
          int gr = (tid & 3) + t * 4;
          u32x4 v = *(const u32x4*)&Cs[row * 136 + gr * 8];
          *(u32x4*)&C16[(size_t)(m0 + half * 64 + row) * ldc + n0 + gr * 8] = v;
        }
      }
      __syncthreads();
    }
  }
}

// ---------------------------------------------------------------------------
// attn_kernel: flash attention in exp2 domain, no running max.
// 512 threads = 8 waves = (q-half qh x kv-quarter kh). Each wave: q=64
// (2 q-groups, K/V frags reused) x kv=32 per 128-kv iter. 16 waves/CU =
// 4 waves/SIMD. P in registers via cvt_pk_bf16 + permlane32_swap.
// Double-buffered K/V, 1 barrier/iter. 2-round cross-wave kv combine at end.
// ---------------------------------------------------------------------------
__global__ __launch_bounds__(512, 4) void attn_kernel(
    const u16* __restrict__ qkvb, u16* __restrict__ catb) {
  __shared__ __align__(16) char smem[71680];
  u16* Ks = (u16*)smem;             // 2 x [kv=128][64+8] u16 = 36,864 B
  u16* Vs = (u16*)(smem + 36864);   // 2 x V^T [d=64][68 u32 swz] = 34,816 B
  int tid = threadIdx.x;
  int lane = tid & 63, wave = tid >> 6;
  int l31 = lane & 31, hi = lane >> 5;
  int qh = wave >> 2, kh = wave & 3;  // q-half, kv-quarter this wave owns
  int bh = blockIdx.x & 31, qt = blockIdx.x >> 5;
  int bb = bh >> 3, h = bh & 7;
  size_t base = (size_t)bb * 2048 * 1536;

  // Q frags (B-operand: col=q=l31, k=hi*8+j), 4 chunks of K=16 over d=64
  bf16x8 qf[2][4];
#pragma unroll
  for (int qg = 0; qg < 2; ++qg) {
    int n = qt * 128 + qh * 64 + qg * 32 + l31;
    const u16* qp = &qkvb[base + (size_t)n * 1536 + h * 64 + hi * 8];
#pragma unroll
    for (int kc = 0; kc < 4; ++kc) qf[qg][kc] = *(const bf16x8*)(qp + kc * 16);
  }

  f32x16 oacc[2][2];  // [qg][dt]
#pragma unroll
  for (int qg = 0; qg < 2; ++qg)
#pragma unroll
    for (int dt = 0; dt < 2; ++dt)
#pragma unroll
      for (int r = 0; r < 16; ++r) oacc[qg][dt][r] = 0.f;
  float lsum[2] = {0.f, 0.f};

  su16x8 kpre[2], v0pre, v1pre;
  int kv_s = tid >> 3, dg_s = tid & 7;  // staging coords (512 threads)

  auto loadKV = [&](int n0k) {
#pragma unroll
    for (int t = 0; t < 2; ++t)
      kpre[t] = *(const su16x8*)&qkvb[base + (size_t)(n0k + kv_s + t * 64) *
                                                1536 +
                                      512 + h * 64 + dg_s * 8];
    {
      const u16* vg =
          &qkvb[base + (size_t)(n0k + kv_s * 2) * 1536 + 1024 + h * 64 +
                dg_s * 8];
      v0pre = *(const su16x8*)vg;
      v1pre = *(const su16x8*)(vg + 1536);
    }
  };

  auto stage = [&](int buf) {
    u16* ksw = Ks + buf * 9216;
    u32* vw = (u32*)(Vs + buf * 8704);
#pragma unroll
    for (int t = 0; t < 2; ++t)
      *(su16x8*)&ksw[(kv_s + t * 64) * 72 + dg_s * 8] = kpre[t];
    {
      int kvg = kv_s >> 2, w2 = kv_s & 3;
#pragma unroll
      for (int j = 0; j < 8; ++j) {
        int d = dg_s * 8 + j;
        vw[d * 68 + ((kvg ^ (dg_s & 7)) << 2) + w2] =
            (u32)v0pre[j] | ((u32)v1pre[j] << 16);
      }
    }
  };

  loadKV(0);
  stage(0);
  for (int kb2 = 0; kb2 < 16; ++kb2) {
    __syncthreads();  // staged writes visible; everyone done with other buf
    int cur = kb2 & 1;
    if (kb2 < 15) loadKV((kb2 + 1) * 128);  // global prefetch, consumed at end
    const u16* ksb = Ks + cur * 9216;
    const u16* vsb = Vs + cur * 8704;
    // ---- S^T tiles = K[our 32 kv] · Q^T, both q-groups ----
    bf16x8 kf[4];
#pragma unroll
    for (int kc = 0; kc < 4; ++kc)
      kf[kc] =
          *(const bf16x8*)&ksb[(kh * 32 + l31) * 72 + kc * 16 + hi * 8];
    f32x16 s0, s1;
#pragma unroll
    for (int r = 0; r < 16; ++r) { s0[r] = 0.f; s1[r] = 0.f; }
    __builtin_amdgcn_s_setprio(1);
#pragma unroll
    for (int kc = 0; kc < 4; ++kc) {
      s0 = mfma32(kf[kc], qf[0][kc], s0);
      s1 = mfma32(kf[kc], qf[1][kc], s1);
    }
    __builtin_amdgcn_s_setprio(0);
    // ---- P = exp2(S^T): lane owns q, kv row=(r&3)+8*(r>>2)+4*hi ----
    bf16x8 pf[2][2];
#pragma unroll
    for (int qg = 0; qg < 2; ++qg) {
      float p[16];
#pragma unroll
      for (int r = 0; r < 16; ++r) p[r] = fexp2(qg ? s1[r] : s0[r]);
      lsum[qg] += ((((p[0] + p[1]) + (p[2] + p[3])) +
                    ((p[4] + p[5]) + (p[6] + p[7]))) +
                   (((p[8] + p[9]) + (p[10] + p[11])) +
                    ((p[12] + p[13]) + (p[14] + p[15]))));
      u32 a0 = pkbf(p[0], p[1]), b0 = pkbf(p[4], p[5]);
      u32 a1 = pkbf(p[2], p[3]), b1 = pkbf(p[6], p[7]);
      u32 a2 = pkbf(p[8], p[9]), b2 = pkbf(p[12], p[13]);
      u32 a3 = pkbf(p[10], p[11]), b3 = pkbf(p[14], p[15]);
      swap32(a0, b0);
      swap32(a1, b1);
      swap32(a2, b2);
      swap32(a3, b3);
      pf[qg][0] = mkfrag(a0, a1, b0, b1);  // own kv [0,16)
      pf[qg][1] = mkfrag(a2, a3, b2, b3);  // own kv [16,32)
    }
    // ---- O += P @ V (V frags shared across both q-groups) ----
    __builtin_amdgcn_s_setprio(1);
#pragma unroll
    for (int kc2 = 0; kc2 < 2; ++kc2) {
      int g = kh * 4 + kc2 * 2 + hi;  // 8-kv granule index in 128-kv tile
#pragma unroll
      for (int dt = 0; dt < 2; ++dt) {
        int d = dt * 32 + l31;
        bf16x8 vf =
            *(const bf16x8*)&vsb[d * 136 + ((g ^ ((d >> 3) & 7)) << 3)];
        oacc[0][dt] = mfma32(pf[0][kc2], vf, oacc[0][dt]);
        oacc[1][dt] = mfma32(pf[1][kc2], vf, oacc[1][dt]);
      }
    }
    __builtin_amdgcn_s_setprio(0);
    if (kb2 < 15) stage(cur ^ 1);  // vmcnt wait lands here, after compute
  }
#pragma unroll
  for (int qg = 0; qg < 2; ++qg) lsum[qg] += __shfl_xor(lsum[qg], 32);

  // ---- cross-wave kv combine: kh{2,3} -> kh{0,1}, then kh1 -> kh0 ----
  float* Of = (float*)smem;            // [4 slots][64 q][68] f32 = 69,632 B
  float* Lf = (float*)(smem + 69632);  // [4 slots][64] f32
  int slot = qh * 2 + (kh & 1);
  __syncthreads();
  if (kh >= 2) {
#pragma unroll
    for (int qg = 0; qg < 2; ++qg) {
#pragma unroll
      for (int dt = 0; dt < 2; ++dt)
#pragma unroll
        for (int r = 0; r < 16; ++r) {
          int qrow = (r & 3) + 8 * (r >> 2) + 4 * hi;
          Of[(slot * 64 + qg * 32 + qrow) * 68 + dt * 32 + l31] =
              oacc[qg][dt][r];
        }
      if (hi == 0) Lf[slot * 64 + qg * 32 + l31] = lsum[qg];
    }
  }
  __syncthreads();
  if (kh < 2) {
#pragma unroll
    for (int qg = 0; qg < 2; ++qg) {
      lsum[qg] += Lf[slot * 64 + qg * 32 + l31];
#pragma unroll
      for (int dt = 0; dt < 2; ++dt)
#pragma unroll
        for (int r = 0; r < 16; ++r) {
          int qrow = (r & 3) + 8 * (r >> 2) + 4 * hi;
          oacc[qg][dt][r] +=
              Of[(slot * 64 + qg * 32 + qrow) * 68 + dt * 32 + l31];
        }
    }
    if (kh == 1) {  // write combined into own slot (already consumed)
#pragma unroll
      for (int qg = 0; qg < 2; ++qg) {
#pragma unroll
        for (int dt = 0; dt < 2; ++dt)
#pragma unroll
          for (int r = 0; r < 16; ++r) {
            int qrow = (r & 3) + 8 * (r >> 2) + 4 * hi;
            Of[(slot * 64 + qg * 32 + qrow) * 68 + dt * 32 + l31] =
                oacc[qg][dt][r];
          }
        if (hi == 0) Lf[slot * 64 + qg * 32 + l31] = lsum[qg];
      }
    }
  }
  __syncthreads();
  if (kh == 0) {
    int oslot = qh * 2 + 1;
#pragma unroll
    for (int qg = 0; qg < 2; ++qg) {
      float lt = lsum[qg] + Lf[oslot * 64 + qg * 32 + l31];
#pragma unroll
      for (int r = 0; r < 16; ++r) {
        int qrow = (r & 3) + 8 * (r >> 2) + 4 * hi;
        float linv = 1.f / __shfl(lt, qrow);
        int qq = qh * 64 + qg * 32 + qrow;
        float o0 = oacc[qg][0][r] +
                   Of[(oslot * 64 + qg * 32 + qrow) * 68 + l31];
        float o1 = oacc[qg][1][r] +
                   Of[(oslot * 64 + qg * 32 + qrow) * 68 + 32 + l31];
        size_t n = (size_t)(bb * 2048 + qt * 128 + qq);
        u16* cp = &catb[n * 768 + h * 64];
        cp[l31] = f2bf(o0 * linv);
        cp[32 + l31] = f2bf(o1 * linv);
      }
    }
  }
}

// ---------------------------------------------------------------------------
extern "C" void kernel_launch(void* const* d_in, const int* in_sizes, int n_in,
                              void* d_out, int out_size, void* d_ws,
                              size_t ws_size, hipStream_t stream) {
  const float* x = (const float*)d_in[0];
  const float* w_qkv = (const float*)d_in[1];
  const float* b_qkv = (const float*)d_in[2];
  const float* w_in = (const float*)d_in[3];
  const float* b_in = (const float*)d_in[4];
  const float* w_out = (const float*)d_in[5];
  const float* b_out = (const float*)d_in[6];
  const float* w_merge = (const float*)d_in[7];
  const float* b_merge = (const float*)d_in[8];
  const float* w_proj = (const float*)d_in[9];
  const float* b_proj = (const float*)d_in[10];

  char* ws = (char*)d_ws;
  u16* xb = (u16*)(ws + 0);               //  4,194,304 B
  u16* qkvb = (u16*)(ws + 4194304);       // 25,165,824 B
  u16* catb = (u16*)(ws + 29360128);      // 12,582,912 B
  u16* wqkvT = (u16*)(ws + 41943040);     //    786,432 B  [1536][256]
  u16* wptT = (u16*)(ws + 42729472);      //    524,288 B  [512][512]
  u16* wmb = (u16*)(ws + 43253760);       //    524,288 B  [512][512]
  u16* wcombT = (u16*)(ws + 43778048);    //    786,432 B  [512][768]
  float* biasc = (float*)(ws + 44564480); //      2,048 B

  prep_ib_kernel<<<800, 256, 0, stream>>>(w_qkv, w_merge, w_proj, b_merge,
                                          b_proj, wqkvT, wptT, wcombT, wmb,
                                          biasc, x, w_in, b_in, w_out, b_out,
                                          xb, catb);
  // qkv = x @ w_qkv + b_qkv; q scaled by SCALE*log2e in epilogue
  gemm_bt<128, 128, 2, 2, 1><<<dim3(12, 64), 256, 0, stream>>>(
      xb, 256, wqkvT, 256, 256, b_qkv, (void*)qkvb, 1536, 1);
  // wcombT[:, :512] = wptT @ w_merge  (= (w_merge @ w_proj_top)^T)
  gemm_bt<64, 64, 2, 2, 2><<<dim3(8, 8), 256, 0, stream>>>(
      wptT, 512, wmb, 512, 512, nullptr, (void*)wcombT, 768, 0);
  attn_kernel<<<512, 512, 0, stream>>>(qkvb, catb);
  // out = catb @ wcombT^T + biasc  (fp32)
  gemm_bt<128, 64, 4, 1, 0><<<dim3(8, 64), 256, 0, stream>>>(
      catb, 768, wcombT, 768, 768, biasc, d_out, 512, 0);
}

// Round 4
// 181.902 us; speedup vs baseline: 1.8850x; 1.8850x over previous
//
#include <hip/hip_runtime.h>

// ---------------------------------------------------------------------------
// MSAAttention fused pipeline (MI355X / gfx950), bf16 MFMA throughout.
//
// out = concat[softmax(qk^T*s)v @ w_merge + b_merge, ib] @ w_proj + b_proj
// Folded: wcombT holds (w_merge@w_proj_top)^T and w_proj_bot^T — the merge
// GEMM is deleted; biasc = b_merge@w_proj_top + b_proj.
// SCALE*log2e folded into q; softmax in exp2 domain, no max-subtraction.
// attn: grid 1024 (64 q/block), 256 threads = 4 waves (q-half x kv-half),
// KVBLK=64 double-buffered (LDS 36 KB) -> 4 blocks/CU = 4 waves/SIMD.
// Persistent VGPR ~64 (oacc 32 + qf 16 + prefetch 16) so launch_bounds(256,4)
// holds without spills (R3 lesson: 512-thr/8-wave variant spilled at 128 cap).
// 32x32x16 MFMA, swapped QK^T (S^T = K·Q^T), P fully in-register
// (v_cvt_pk_bf16_f32 + v_permlane32_swap_b32). kv-half combine via LDS once.
// ---------------------------------------------------------------------------

typedef unsigned short u16;
typedef unsigned int u32;
typedef __bf16 bf16x8 __attribute__((ext_vector_type(8)));
typedef u16 su16x8 __attribute__((ext_vector_type(8)));
typedef u16 su16x4 __attribute__((ext_vector_type(4)));
typedef u32 u32x4 __attribute__((ext_vector_type(4)));
typedef float f32x4 __attribute__((ext_vector_type(4)));
typedef float f32x16 __attribute__((ext_vector_type(16)));

__device__ __forceinline__ u16 f2bf(float f) {
  union { __bf16 h; u16 u; } v;
  v.h = (__bf16)f;
  return v.u;
}

__device__ __forceinline__ float fexp2(float x) {
#if __has_builtin(__builtin_amdgcn_exp2f)
  return __builtin_amdgcn_exp2f(x);
#else
  return __expf(x * 0.6931471805599453f);
#endif
}

__device__ __forceinline__ f32x4 zero4() {
  f32x4 v = {0.f, 0.f, 0.f, 0.f};
  return v;
}

__device__ __forceinline__ f32x4 mfma16(bf16x8 a, bf16x8 b, f32x4 c) {
  return __builtin_amdgcn_mfma_f32_16x16x32_bf16(a, b, c, 0, 0, 0);
}

__device__ __forceinline__ f32x16 mfma32(bf16x8 a, bf16x8 b, f32x16 c) {
  return __builtin_amdgcn_mfma_f32_32x32x16_bf16(a, b, c, 0, 0, 0);
}

// pack two f32 -> one u32 of two bf16 (lo = a, hi = b)
__device__ __forceinline__ u32 pkbf(float a, float b) {
  u32 r;
  asm("v_cvt_pk_bf16_f32 %0, %1, %2" : "=v"(r) : "v"(a), "v"(b));
  return r;
}

// exchange a's hi-lanes with b's lo-lanes
__device__ __forceinline__ void swap32(u32& a, u32& b) {
  asm("v_permlane32_swap_b32 %0, %1" : "+v"(a), "+v"(b));
}

__device__ __forceinline__ bf16x8 mkfrag(u32 w0, u32 w1, u32 w2, u32 w3) {
  union { u32 u[4]; bf16x8 v; } x;
  x.u[0] = w0; x.u[1] = w1; x.u[2] = w2; x.u[3] = w3;
  return x.v;
}

// ---------------------------------------------------------------------------
// prep_ib_kernel (800 blocks): prep paths (0..287) + ib paths (288..799).
// ---------------------------------------------------------------------------
__global__ __launch_bounds__(256) void prep_ib_kernel(
    const float* __restrict__ w_qkv, const float* __restrict__ w_merge,
    const float* __restrict__ w_proj, const float* __restrict__ b_merge,
    const float* __restrict__ b_proj, u16* __restrict__ wqkvT,
    u16* __restrict__ wptT, u16* __restrict__ wcombT, u16* __restrict__ wmb,
    float* __restrict__ biasc, const float* __restrict__ x,
    const float* __restrict__ w_in, const float* __restrict__ b_in,
    const float* __restrict__ w_out, const float* __restrict__ b_out,
    u16* __restrict__ xb, u16* __restrict__ catb) {
  __shared__ __align__(16) char smem[35456];
  int blk = blockIdx.x, tid = threadIdx.x;
  if (blk < 192) {
    const float* src;
    int lsrc, ldd, r0, c0;
    u16* dst;
    if (blk < 96) {
      src = w_qkv; lsrc = 1536; dst = wqkvT; ldd = 256;
      r0 = (blk & 3) * 64; c0 = (blk >> 2) * 64;
    } else if (blk < 160) {
      int b2 = blk - 96;
      src = w_proj; lsrc = 512; dst = wptT; ldd = 512;
      r0 = (b2 & 7) * 64; c0 = (b2 >> 3) * 64;
    } else {
      int b2 = blk - 160;
      src = w_proj + 512 * 512; lsrc = 512; dst = wcombT + 512; ldd = 768;
      r0 = (b2 & 3) * 64; c0 = (b2 >> 2) * 64;
    }
    u16* Ts = (u16*)smem;  // [64][68]
    int rr = tid >> 4, cc4 = (tid & 15) * 4;
#pragma unroll
    for (int rep = 0; rep < 4; ++rep) {
      int r = rr + rep * 16;
      float4 v = *(const float4*)&src[(size_t)(r0 + r) * lsrc + c0 + cc4];
      su16x4 pk = {f2bf(v.x), f2bf(v.y), f2bf(v.z), f2bf(v.w)};
      *(su16x4*)&Ts[r * 68 + cc4] = pk;
    }
    __syncthreads();
    int c = tid & 63, seg = tid >> 6;
    u16 tmp[16];
#pragma unroll
    for (int k = 0; k < 16; ++k) tmp[k] = Ts[(seg * 16 + k) * 68 + c];
    *(su16x8*)&dst[(size_t)(c0 + c) * ldd + r0 + seg * 16] = *(su16x8*)tmp;
    *(su16x8*)&dst[(size_t)(c0 + c) * ldd + r0 + seg * 16 + 8] =
        *(su16x8*)(tmp + 8);
  } else if (blk < 256) {
    int b2 = blk - 192;
#pragma unroll
    for (int rep = 0; rep < 4; ++rep) {
      int i = b2 * 4096 + rep * 1024 + tid * 4;
      float4 v = *(const float4*)&w_merge[i];
      su16x4 pk = {f2bf(v.x), f2bf(v.y), f2bf(v.z), f2bf(v.w)};
      *(su16x4*)&wmb[i] = pk;
    }
  } else if (blk < 288) {
    int col0 = (blk - 256) * 16;
    float(*red)[17] = (float(*)[17])smem;
    int kr = tid >> 4, cc = tid & 15;
    float s = 0.f;
#pragma unroll 4
    for (int j = 0; j < 32; ++j) {
      int k = kr + j * 16;
      s += b_merge[k] * w_proj[(size_t)k * 512 + col0 + cc];
    }
    red[kr][cc] = s;
    __syncthreads();
    if (kr == 0) {
      float a = b_proj[col0 + cc];
#pragma unroll
      for (int t = 0; t < 16; ++t) a += red[t][cc];
      biasc[col0 + cc] = a;
    }
  } else {
    int ib = blk - 288;
    float* wi = (float*)smem;            // 256
    float* wo = (float*)(smem + 1024);   // 256
    float* bi = (float*)(smem + 2048);   // 16
    float* bo = (float*)(smem + 2112);   // 16
    float(*xs)[260] = (float(*)[260])(smem + 2176);
    float(*hs)[260] = (float(*)[260])(smem + 18816);
    wi[tid] = w_in[tid];
    wo[tid] = w_out[tid];
    if (tid < 16) { bi[tid] = b_in[tid]; bo[tid] = b_out[tid]; }
    size_t blkoff = (size_t)ib * 4096;
#pragma unroll
    for (int i = 0; i < 4; ++i) {
      int f = (tid + i * 256) * 4;
      float4 v = *(const float4*)&x[blkoff + f];
      int tok = f >> 8, p = f & 255;
      *(float4*)&xs[tok][p] = v;
      su16x4 pk = {f2bf(v.x), f2bf(v.y), f2bf(v.z), f2bf(v.w)};
      *(su16x4*)&xb[blkoff + f] = pk;
    }
    __syncthreads();
    int t = tid >> 4, p2 = tid & 15;
#pragma unroll
    for (int p1 = 0; p1 < 16; ++p1) {
      float a = bi[p2];
#pragma unroll
      for (int k = 0; k < 16; ++k) a += xs[t][p1 * 16 + k] * wi[k * 16 + p2];
      hs[t][p1 * 16 + p2] = a / (1.f + __expf(-a));
    }
    __syncthreads();
    size_t tok = (size_t)ib * 16 + t;
#pragma unroll
    for (int p1 = 0; p1 < 16; ++p1) {
      float o = bo[p2];
#pragma unroll
      for (int j = 0; j < 16; ++j) o += hs[t][p1 * 16 + j] * wo[j * 16 + p2];
      catb[tok * 768 + 512 + p1 * 16 + p2] = f2bf(o);
    }
  }
}

// ---------------------------------------------------------------------------
// gemm_bt: C[TM-tile][TN-tile] = A[m][k] @ BT[n][k]^T  (both row-major, k-inner)
// OUTMODE 0: f32 out (+bias). 1: bf16 out via LDS-staged b128 stores (+bias,
// scaleQ multiplies cols<512 by SCALE*log2e). 2: bf16 scatter (small tiles).
// ---------------------------------------------------------------------------
template <int TM, int TN, int WGM, int WGN, int OUTMODE>
__global__ __launch_bounds__(256) void gemm_bt(
    const u16* __restrict__ A, int lda, const u16* __restrict__ BT, int ldb,
    int kcount, const float* __restrict__ bias, void* __restrict__ Co, int ldc,
    int scaleQ) {
  constexpr int NROWS = TM + TN;
  constexpr int NLD = NROWS / 64;
  constexpr int MT = TM / WGM / 16;
  constexpr int NT = TN / WGN / 16;
  __shared__ __align__(16) u16 S[NROWS * 40];
  int tid = threadIdx.x;
  int lane = tid & 63, wave = tid >> 6;
  int c = lane & 15, g4 = lane >> 4;
  int m0 = blockIdx.y * TM, n0 = blockIdx.x * TN;
  int wm = (wave / WGN) * (TM / WGM), wn = (wave % WGN) * (TN / WGN);
  f32x4 acc[MT][NT];
#pragma unroll
  for (int a = 0; a < MT; ++a)
#pragma unroll
    for (int b = 0; b < NT; ++b) acc[a][b] = zero4();

  su16x8 pre[NLD];
#pragma unroll
  for (int t = 0; t < NLD; ++t) {
    int gsl = t * 256 + tid;
    int row = gsl >> 2, kg = gsl & 3;
    const u16* p = row < TM ? &A[(size_t)(m0 + row) * lda + kg * 8]
                            : &BT[(size_t)(n0 + row - TM) * ldb + kg * 8];
    pre[t] = *(const su16x8*)p;
  }

  for (int kb = 0; kb < kcount; kb += 32) {
    __syncthreads();
#pragma unroll
    for (int t = 0; t < NLD; ++t) {
      int gsl = t * 256 + tid;
      int row = gsl >> 2, kg = gsl & 3;
      *(su16x8*)&S[row * 40 + kg * 8] = pre[t];
    }
    __syncthreads();
    if (kb + 32 < kcount) {
#pragma unroll
      for (int t = 0; t < NLD; ++t) {
        int gsl = t * 256 + tid;
        int row = gsl >> 2, kg = gsl & 3;
        const u16* p =
            row < TM ? &A[(size_t)(m0 + row) * lda + kb + 32 + kg * 8]
                     : &BT[(size_t)(n0 + row - TM) * ldb + kb + 32 + kg * 8];
        pre[t] = *(const su16x8*)p;
      }
    }
    bf16x8 af[MT], bf[NT];
#pragma unroll
    for (int mt = 0; mt < MT; ++mt)
      af[mt] = *(const bf16x8*)&S[(wm + mt * 16 + c) * 40 + g4 * 8];
#pragma unroll
    for (int nt = 0; nt < NT; ++nt)
      bf[nt] = *(const bf16x8*)&S[(TM + wn + nt * 16 + c) * 40 + g4 * 8];
#pragma unroll
    for (int mt = 0; mt < MT; ++mt)
#pragma unroll
      for (int nt = 0; nt < NT; ++nt)
        acc[mt][nt] = mfma16(af[mt], bf[nt], acc[mt][nt]);
  }

  if (OUTMODE == 0) {
    float* Cf = (float*)Co;
#pragma unroll
    for (int nt = 0; nt < NT; ++nt) {
      int col = n0 + wn + nt * 16 + c;
      float bv = bias ? bias[col] : 0.f;
#pragma unroll
      for (int mt = 0; mt < MT; ++mt)
#pragma unroll
        for (int i = 0; i < 4; ++i)
          Cf[(size_t)(m0 + wm + mt * 16 + g4 * 4 + i) * ldc + col] =
              acc[mt][nt][i] + bv;
    }
  } else if (OUTMODE == 2) {
    u16* C16 = (u16*)Co;
#pragma unroll
    for (int nt = 0; nt < NT; ++nt)
#pragma unroll
      for (int mt = 0; mt < MT; ++mt)
#pragma unroll
        for (int i = 0; i < 4; ++i)
          C16[(size_t)(m0 + wm + mt * 16 + g4 * 4 + i) * ldc + n0 + wn +
              nt * 16 + c] = f2bf(acc[mt][nt][i]);
  } else {
    // OUTMODE 1: requires TM==128, TN==128, WGM==2
    u16* C16 = (u16*)Co;
    u16* Cs = S;  // [64][136] per half
    __syncthreads();
#pragma unroll
    for (int half = 0; half < 2; ++half) {
      if ((wave >> 1) == half) {
#pragma unroll
        for (int nt = 0; nt < NT; ++nt) {
          int col = n0 + wn + nt * 16 + c;
          float bv = bias ? bias[col] : 0.f;
          float sc = (scaleQ && col < 512) ? 0.18033688011112042f : 1.f;
#pragma unroll
          for (int mt = 0; mt < MT; ++mt)
#pragma unroll
            for (int i = 0; i < 4; ++i)
              Cs[(mt * 16 + g4 * 4 + i) * 136 + wn + nt * 16 + c] =
                  f2bf((acc[mt][nt][i] + bv) * sc);
        }
      }
      __syncthreads();
      {
        int row = tid >> 2;
#pragma unroll
        for (int t = 0; t < 4; ++t) {
          int gr = (tid & 3) + t * 4;
          u32x4 v = *(const u32x4*)&Cs[row * 136 + gr * 8];
          *(u32x4*)&C16[(size_t)(m0 + half * 64 + row) * ldc + n0 + gr * 8] = v;
        }
      }
      __syncthreads();
    }
  }
}

// ---------------------------------------------------------------------------
// attn_kernel: flash attention in exp2 domain, no running max.
// Grid 1024 = bb(4) x h(8) x qt(32), 64 q per block. 256 threads = 4 waves
// (q-half qh x kv-half kh). KVBLK=64 double-buffered: LDS 36 KB -> 4
// blocks/CU = 16 waves/CU = 4 waves/SIMD. Per wave-iter: 8 MFMA, 8
// conflict-free b128 LDS reads. P in registers via cvt_pk + permlane32_swap.
// 1 barrier/iter; kv-half O/l combine via LDS once at the end.
// ---------------------------------------------------------------------------
__global__ __launch_bounds__(256, 4) void attn_kernel(
    const u16* __restrict__ qkvb, u16* __restrict__ catb) {
  __shared__ __align__(16) u16 Ks[2 * 4608];  // 2 x [kv=64][64+8] u16
  __shared__ __align__(16) u16 Vs[2 * 4608];  // 2 x V^T [d=64][36 u32 swz]
  int tid = threadIdx.x;
  int lane = tid & 63, wave = tid >> 6;
  int l31 = lane & 31, hi = lane >> 5;
  int qh = wave >> 1, kh = wave & 1;  // q-half (32 q), kv-half (32 kv)
  int bh = blockIdx.x & 31, qt = blockIdx.x >> 5;
  int bb = bh >> 3, h = bh & 7;
  size_t base = (size_t)bb * 2048 * 1536;

  // Q frags (B-operand: col=q=l31, k=hi*8+j), 4 chunks of K=16 over d=64
  bf16x8 qf[4];
  {
    int n = qt * 64 + qh * 32 + l31;
    const u16* qp = &qkvb[base + (size_t)n * 1536 + h * 64 + hi * 8];
#pragma unroll
    for (int kc = 0; kc < 4; ++kc) qf[kc] = *(const bf16x8*)(qp + kc * 16);
  }

  f32x16 oacc[2];  // [dt]
#pragma unroll
  for (int dt = 0; dt < 2; ++dt)
#pragma unroll
    for (int r = 0; r < 16; ++r) oacc[dt][r] = 0.f;
  float lsum = 0.f;

  su16x8 kpre[2], v0pre, v1pre;
  int kv_s = tid >> 3, dg_s = tid & 7;  // staging coords

  auto loadKV = [&](int n0k) {
#pragma unroll
    for (int t = 0; t < 2; ++t)
      kpre[t] = *(const su16x8*)&qkvb[base + (size_t)(n0k + kv_s + t * 32) *
                                                1536 +
                                      512 + h * 64 + dg_s * 8];
    {
      const u16* vg = &qkvb[base + (size_t)(n0k + kv_s * 2) * 1536 + 1024 +
                            h * 64 + dg_s * 8];
      v0pre = *(const su16x8*)vg;
      v1pre = *(const su16x8*)(vg + 1536);
    }
  };

  auto stage = [&](int buf) {
    u16* ksw = Ks + buf * 4608;
    u32* vw = (u32*)(Vs + buf * 4608);
#pragma unroll
    for (int t = 0; t < 2; ++t)
      *(su16x8*)&ksw[(kv_s + t * 32) * 72 + dg_s * 8] = kpre[t];
    {
      int kvg = kv_s >> 2, w2 = kv_s & 3;  // pair granule, pair-in-granule
#pragma unroll
      for (int j = 0; j < 8; ++j) {
        int d = dg_s * 8 + j;
        vw[d * 36 + ((kvg ^ dg_s) << 2) + w2] =
            (u32)v0pre[j] | ((u32)v1pre[j] << 16);
      }
    }
  };

  loadKV(0);
  stage(0);
  for (int kb2 = 0; kb2 < 32; ++kb2) {
    __syncthreads();  // staged writes visible; everyone done with other buf
    int cur = kb2 & 1;
    if (kb2 < 31) loadKV((kb2 + 1) * 64);  // global prefetch, consumed at end
    const u16* ksb = Ks + cur * 4608;
    const u16* vsb = Vs + cur * 4608;
    // ---- S^T tile = K[own 32 kv] · Q^T ----
    bf16x8 kf[4];
#pragma unroll
    for (int kc = 0; kc < 4; ++kc)
      kf[kc] = *(const bf16x8*)&ksb[(kh * 32 + l31) * 72 + kc * 16 + hi * 8];
    f32x16 sacc;
#pragma unroll
    for (int r = 0; r < 16; ++r) sacc[r] = 0.f;
    __builtin_amdgcn_s_setprio(1);
#pragma unroll
    for (int kc = 0; kc < 4; ++kc) sacc = mfma32(kf[kc], qf[kc], sacc);
    __builtin_amdgcn_s_setprio(0);
    // ---- P = exp2(S^T): lane owns q=l31, kv row=(r&3)+8*(r>>2)+4*hi ----
    float p[16];
#pragma unroll
    for (int r = 0; r < 16; ++r) p[r] = fexp2(sacc[r]);
    lsum += ((((p[0] + p[1]) + (p[2] + p[3])) +
              ((p[4] + p[5]) + (p[6] + p[7]))) +
             (((p[8] + p[9]) + (p[10] + p[11])) +
              ((p[12] + p[13]) + (p[14] + p[15]))));
    u32 a0 = pkbf(p[0], p[1]), b0 = pkbf(p[4], p[5]);
    u32 a1 = pkbf(p[2], p[3]), b1 = pkbf(p[6], p[7]);
    u32 a2 = pkbf(p[8], p[9]), b2 = pkbf(p[12], p[13]);
    u32 a3 = pkbf(p[10], p[11]), b3 = pkbf(p[14], p[15]);
    swap32(a0, b0);
    swap32(a1, b1);
    swap32(a2, b2);
    swap32(a3, b3);
    bf16x8 pf0 = mkfrag(a0, a1, b0, b1);  // own kv [0,16)
    bf16x8 pf1 = mkfrag(a2, a3, b2, b3);  // own kv [16,32)
    // ---- O += P @ V ----
    __builtin_amdgcn_s_setprio(1);
#pragma unroll
    for (int kc2 = 0; kc2 < 2; ++kc2) {
      int g = kh * 4 + kc2 * 2 + hi;  // 8-kv granule index in 64-kv tile
#pragma unroll
      for (int dt = 0; dt < 2; ++dt) {
        int d = dt * 32 + l31;
        bf16x8 vf =
            *(const bf16x8*)&vsb[d * 72 + ((g ^ ((d >> 3) & 7)) << 3)];
        oacc[dt] = mfma32(kc2 ? pf1 : pf0, vf, oacc[dt]);
      }
    }
    __builtin_amdgcn_s_setprio(0);
    if (kb2 < 31) stage(cur ^ 1);  // vmcnt wait lands here, after compute
  }
  lsum += __shfl_xor(lsum, 32);

  // ---- cross-wave kv-half combine (reuse LDS; once per block) ----
  __syncthreads();
  float* Of = (float*)Ks;  // [2 qh][32 q][68] f32 = 17,408 B
  float* Lf = (float*)Vs;  // [2 qh][32] f32
  if (kh == 1) {
#pragma unroll
    for (int dt = 0; dt < 2; ++dt)
#pragma unroll
      for (int r = 0; r < 16; ++r) {
        int qrow = (r & 3) + 8 * (r >> 2) + 4 * hi;
        Of[(qh * 32 + qrow) * 68 + dt * 32 + l31] = oacc[dt][r];
      }
    if (hi == 0) Lf[qh * 32 + l31] = lsum;
  }
  __syncthreads();
  if (kh == 0) {
    float lt = lsum + Lf[qh * 32 + l31];
#pragma unroll
    for (int r = 0; r < 16; ++r) {
      int qrow = (r & 3) + 8 * (r >> 2) + 4 * hi;
      float linv = 1.f / __shfl(lt, qrow);
      float o0 = oacc[0][r] + Of[(qh * 32 + qrow) * 68 + l31];
      float o1 = oacc[1][r] + Of[(qh * 32 + qrow) * 68 + 32 + l31];
      size_t n = (size_t)(bb * 2048 + qt * 64 + qh * 32 + qrow);
      u16* cp = &catb[n * 768 + h * 64];
      cp[l31] = f2bf(o0 * linv);
      cp[32 + l31] = f2bf(o1 * linv);
    }
  }
}

// ---------------------------------------------------------------------------
extern "C" void kernel_launch(void* const* d_in, const int* in_sizes, int n_in,
                              void* d_out, int out_size, void* d_ws,
                              size_t ws_size, hipStream_t stream) {
  const float* x = (const float*)d_in[0];
  const float* w_qkv = (const float*)d_in[1];
  const float* b_qkv = (const float*)d_in[2];
  const float* w_in = (const float*)d_in[3];
  const float* b_in = (const float*)d_in[4];
  const float* w_out = (const float*)d_in[5];
  const float* b_out = (const float*)d_in[6];
  const float* w_merge = (const float*)d_in[7];
  const float* b_merge = (const float*)d_in[8];
  const float* w_proj = (const float*)d_in[9];
  const float* b_proj = (const float*)d_in[10];

  char* ws = (char*)d_ws;
  u16* xb = (u16*)(ws + 0);               //  4,194,304 B
  u16* qkvb = (u16*)(ws + 4194304);       // 25,165,824 B
  u16* catb = (u16*)(ws + 29360128);      // 12,582,912 B
  u16* wqkvT = (u16*)(ws + 41943040);     //    786,432 B  [1536][256]
  u16* wptT = (u16*)(ws + 42729472);      //    524,288 B  [512][512]
  u16* wmb = (u16*)(ws + 43253760);       //    524,288 B  [512][512]
  u16* wcombT = (u16*)(ws + 43778048);    //    786,432 B  [512][768]
  float* biasc = (float*)(ws + 44564480); //      2,048 B

  prep_ib_kernel<<<800, 256, 0, stream>>>(w_qkv, w_merge, w_proj, b_merge,
                                          b_proj, wqkvT, wptT, wcombT, wmb,
                                          biasc, x, w_in, b_in, w_out, b_out,
                                          xb, catb);
  // qkv = x @ w_qkv + b_qkv; q scaled by SCALE*log2e in epilogue
  gemm_bt<128, 128, 2, 2, 1><<<dim3(12, 64), 256, 0, stream>>>(
      xb, 256, wqkvT, 256, 256, b_qkv, (void*)qkvb, 1536, 1);
  // wcombT[:, :512] = wptT @ w_merge  (= (w_merge @ w_proj_top)^T)
  gemm_bt<64, 64, 2, 2, 2><<<dim3(8, 8), 256, 0, stream>>>(
      wptT, 512, wmb, 512, 512, nullptr, (void*)wcombT, 768, 0);
  attn_kernel<<<1024, 256, 0, stream>>>(qkvb, catb);
  // out = catb @ wcombT^T + biasc  (fp32)
  gemm_bt<128, 64, 4, 1, 0><<<dim3(8, 64), 256, 0, stream>>>(
      catb, 768, wcombT, 768, 768, biasc, d_out, 512, 0);
}

// Round 5
// 175.854 us; speedup vs baseline: 1.9498x; 1.0344x over previous
//
#include <hip/hip_runtime.h>

// ---------------------------------------------------------------------------
// MSAAttention fused pipeline (MI355X / gfx950), bf16 MFMA throughout.
//
// out = concat[softmax(qk^T*s)v @ w_merge + b_merge, ib] @ w_proj + b_proj
// Folded: wcombT holds (w_merge@w_proj_top)^T and w_proj_bot^T — the merge
// GEMM is deleted; biasc = b_merge@w_proj_top + b_proj.
// SCALE*log2e folded into q; softmax in exp2 domain, no max-subtraction.
// attn: R1 structure (best measured): grid 512, 4 waves x 32q x full-KV,
// KVBLK=128 double-buffered, 32x32x16 MFMA, swapped QK^T (S^T = K·Q^T),
// P fully in-register (v_cvt_pk_bf16_f32 + v_permlane32_swap_b32).
// Only change vs R1: V-staging swizzle widened &3 -> &7 on BOTH write and
// read (R1's &3 was a 4-way write-bank conflict, 3.1M cycles; R2 verified
// &7 lands ~1M). Lesson from R2/R4: LDS-traffic and occupancy "fixes" that
// shrink the per-wave instruction window regress — keep the deep R1 body.
// ---------------------------------------------------------------------------

typedef unsigned short u16;
typedef unsigned int u32;
typedef __bf16 bf16x8 __attribute__((ext_vector_type(8)));
typedef u16 su16x8 __attribute__((ext_vector_type(8)));
typedef u16 su16x4 __attribute__((ext_vector_type(4)));
typedef u32 u32x4 __attribute__((ext_vector_type(4)));
typedef float f32x4 __attribute__((ext_vector_type(4)));
typedef float f32x16 __attribute__((ext_vector_type(16)));

__device__ __forceinline__ u16 f2bf(float f) {
  union { __bf16 h; u16 u; } v;
  v.h = (__bf16)f;
  return v.u;
}

__device__ __forceinline__ float fexp2(float x) {
#if __has_builtin(__builtin_amdgcn_exp2f)
  return __builtin_amdgcn_exp2f(x);
#else
  return __expf(x * 0.6931471805599453f);
#endif
}

__device__ __forceinline__ f32x4 zero4() {
  f32x4 v = {0.f, 0.f, 0.f, 0.f};
  return v;
}

__device__ __forceinline__ f32x4 mfma16(bf16x8 a, bf16x8 b, f32x4 c) {
  return __builtin_amdgcn_mfma_f32_16x16x32_bf16(a, b, c, 0, 0, 0);
}

__device__ __forceinline__ f32x16 mfma32(bf16x8 a, bf16x8 b, f32x16 c) {
  return __builtin_amdgcn_mfma_f32_32x32x16_bf16(a, b, c, 0, 0, 0);
}

// pack two f32 -> one u32 of two bf16 (lo = a, hi = b)
__device__ __forceinline__ u32 pkbf(float a, float b) {
  u32 r;
  asm("v_cvt_pk_bf16_f32 %0, %1, %2" : "=v"(r) : "v"(a), "v"(b));
  return r;
}

// exchange a's hi-lanes with b's lo-lanes
__device__ __forceinline__ void swap32(u32& a, u32& b) {
  asm("v_permlane32_swap_b32 %0, %1" : "+v"(a), "+v"(b));
}

__device__ __forceinline__ bf16x8 mkfrag(u32 w0, u32 w1, u32 w2, u32 w3) {
  union { u32 u[4]; bf16x8 v; } x;
  x.u[0] = w0; x.u[1] = w1; x.u[2] = w2; x.u[3] = w3;
  return x.v;
}

// ---------------------------------------------------------------------------
// prep_ib_kernel (800 blocks): prep paths (0..287) + ib paths (288..799).
// ---------------------------------------------------------------------------
__global__ __launch_bounds__(256) void prep_ib_kernel(
    const float* __restrict__ w_qkv, const float* __restrict__ w_merge,
    const float* __restrict__ w_proj, const float* __restrict__ b_merge,
    const float* __restrict__ b_proj, u16* __restrict__ wqkvT,
    u16* __restrict__ wptT, u16* __restrict__ wcombT, u16* __restrict__ wmb,
    float* __restrict__ biasc, const float* __restrict__ x,
    const float* __restrict__ w_in, const float* __restrict__ b_in,
    const float* __restrict__ w_out, const float* __restrict__ b_out,
    u16* __restrict__ xb, u16* __restrict__ catb) {
  __shared__ __align__(16) char smem[35456];
  int blk = blockIdx.x, tid = threadIdx.x;
  if (blk < 192) {
    const float* src;
    int lsrc, ldd, r0, c0;
    u16* dst;
    if (blk < 96) {
      src = w_qkv; lsrc = 1536; dst = wqkvT; ldd = 256;
      r0 = (blk & 3) * 64; c0 = (blk >> 2) * 64;
    } else if (blk < 160) {
      int b2 = blk - 96;
      src = w_proj; lsrc = 512; dst = wptT; ldd = 512;
      r0 = (b2 & 7) * 64; c0 = (b2 >> 3) * 64;
    } else {
      int b2 = blk - 160;
      src = w_proj + 512 * 512; lsrc = 512; dst = wcombT + 512; ldd = 768;
      r0 = (b2 & 3) * 64; c0 = (b2 >> 2) * 64;
    }
    u16* Ts = (u16*)smem;  // [64][68]
    int rr = tid >> 4, cc4 = (tid & 15) * 4;
#pragma unroll
    for (int rep = 0; rep < 4; ++rep) {
      int r = rr + rep * 16;
      float4 v = *(const float4*)&src[(size_t)(r0 + r) * lsrc + c0 + cc4];
      su16x4 pk = {f2bf(v.x), f2bf(v.y), f2bf(v.z), f2bf(v.w)};
      *(su16x4*)&Ts[r * 68 + cc4] = pk;
    }
    __syncthreads();
    int c = tid & 63, seg = tid >> 6;
    u16 tmp[16];
#pragma unroll
    for (int k = 0; k < 16; ++k) tmp[k] = Ts[(seg * 16 + k) * 68 + c];
    *(su16x8*)&dst[(size_t)(c0 + c) * ldd + r0 + seg * 16] = *(su16x8*)tmp;
    *(su16x8*)&dst[(size_t)(c0 + c) * ldd + r0 + seg * 16 + 8] =
        *(su16x8*)(tmp + 8);
  } else if (blk < 256) {
    int b2 = blk - 192;
#pragma unroll
    for (int rep = 0; rep < 4; ++rep) {
      int i = b2 * 4096 + rep * 1024 + tid * 4;
      float4 v = *(const float4*)&w_merge[i];
      su16x4 pk = {f2bf(v.x), f2bf(v.y), f2bf(v.z), f2bf(v.w)};
      *(su16x4*)&wmb[i] = pk;
    }
  } else if (blk < 288) {
    int col0 = (blk - 256) * 16;
    float(*red)[17] = (float(*)[17])smem;
    int kr = tid >> 4, cc = tid & 15;
    float s = 0.f;
#pragma unroll 4
    for (int j = 0; j < 32; ++j) {
      int k = kr + j * 16;
      s += b_merge[k] * w_proj[(size_t)k * 512 + col0 + cc];
    }
    red[kr][cc] = s;
    __syncthreads();
    if (kr == 0) {
      float a = b_proj[col0 + cc];
#pragma unroll
      for (int t = 0; t < 16; ++t) a += red[t][cc];
      biasc[col0 + cc] = a;
    }
  } else {
    int ib = blk - 288;
    float* wi = (float*)smem;            // 256
    float* wo = (float*)(smem + 1024);   // 256
    float* bi = (float*)(smem + 2048);   // 16
    float* bo = (float*)(smem + 2112);   // 16
    float(*xs)[260] = (float(*)[260])(smem + 2176);
    float(*hs)[260] = (float(*)[260])(smem + 18816);
    wi[tid] = w_in[tid];
    wo[tid] = w_out[tid];
    if (tid < 16) { bi[tid] = b_in[tid]; bo[tid] = b_out[tid]; }
    size_t blkoff = (size_t)ib * 4096;
#pragma unroll
    for (int i = 0; i < 4; ++i) {
      int f = (tid + i * 256) * 4;
      float4 v = *(const float4*)&x[blkoff + f];
      int tok = f >> 8, p = f & 255;
      *(float4*)&xs[tok][p] = v;
      su16x4 pk = {f2bf(v.x), f2bf(v.y), f2bf(v.z), f2bf(v.w)};
      *(su16x4*)&xb[blkoff + f] = pk;
    }
    __syncthreads();
    int t = tid >> 4, p2 = tid & 15;
#pragma unroll
    for (int p1 = 0; p1 < 16; ++p1) {
      float a = bi[p2];
#pragma unroll
      for (int k = 0; k < 16; ++k) a += xs[t][p1 * 16 + k] * wi[k * 16 + p2];
      hs[t][p1 * 16 + p2] = a / (1.f + __expf(-a));
    }
    __syncthreads();
    size_t tok = (size_t)ib * 16 + t;
#pragma unroll
    for (int p1 = 0; p1 < 16; ++p1) {
      float o = bo[p2];
#pragma unroll
      for (int j = 0; j < 16; ++j) o += hs[t][p1 * 16 + j] * wo[j * 16 + p2];
      catb[tok * 768 + 512 + p1 * 16 + p2] = f2bf(o);
    }
  }
}

// ---------------------------------------------------------------------------
// gemm_bt: C[TM-tile][TN-tile] = A[m][k] @ BT[n][k]^T  (both row-major, k-inner)
// OUTMODE 0: f32 out (+bias). 1: bf16 out via LDS-staged b128 stores (+bias,
// scaleQ multiplies cols<512 by SCALE*log2e). 2: bf16 scatter (small tiles).
// ---------------------------------------------------------------------------
template <int TM, int TN, int WGM, int WGN, int OUTMODE>
__global__ __launch_bounds__(256) void gemm_bt(
    const u16* __restrict__ A, int lda, const u16* __restrict__ BT, int ldb,
    int kcount, const float* __restrict__ bias, void* __restrict__ Co, int ldc,
    int scaleQ) {
  constexpr int NROWS = TM + TN;
  constexpr int NLD = NROWS / 64;
  constexpr int MT = TM / WGM / 16;
  constexpr int NT = TN / WGN / 16;
  __shared__ __align__(16) u16 S[NROWS * 40];
  int tid = threadIdx.x;
  int lane = tid & 63, wave = tid >> 6;
  int c = lane & 15, g4 = lane >> 4;
  int m0 = blockIdx.y * TM, n0 = blockIdx.x * TN;
  int wm = (wave / WGN) * (TM / WGM), wn = (wave % WGN) * (TN / WGN);
  f32x4 acc[MT][NT];
#pragma unroll
  for (int a = 0; a < MT; ++a)
#pragma unroll
    for (int b = 0; b < NT; ++b) acc[a][b] = zero4();

  su16x8 pre[NLD];
#pragma unroll
  for (int t = 0; t < NLD; ++t) {
    int gsl = t * 256 + tid;
    int row = gsl >> 2, kg = gsl & 3;
    const u16* p = row < TM ? &A[(size_t)(m0 + row) * lda + kg * 8]
                            : &BT[(size_t)(n0 + row - TM) * ldb + kg * 8];
    pre[t] = *(const su16x8*)p;
  }

  for (int kb = 0; kb < kcount; kb += 32) {
    __syncthreads();
#pragma unroll
    for (int t = 0; t < NLD; ++t) {
      int gsl = t * 256 + tid;
      int row = gsl >> 2, kg = gsl & 3;
      *(su16x8*)&S[row * 40 + kg * 8] = pre[t];
    }
    __syncthreads();
    if (kb + 32 < kcount) {
#pragma unroll
      for (int t = 0; t < NLD; ++t) {
        int gsl = t * 256 + tid;
        int row = gsl >> 2, kg = gsl & 3;
        const u16* p =
            row < TM ? &A[(size_t)(m0 + row) * lda + kb + 32 + kg * 8]
                     : &BT[(size_t)(n0 + row - TM) * ldb + kb + 32 + kg * 8];
        pre[t] = *(const su16x8*)p;
      }
    }
    bf16x8 af[MT], bf[NT];
#pragma unroll
    for (int mt = 0; mt < MT; ++mt)
      af[mt] = *(const bf16x8*)&S[(wm + mt * 16 + c) * 40 + g4 * 8];
#pragma unroll
    for (int nt = 0; nt < NT; ++nt)
      bf[nt] = *(const bf16x8*)&S[(TM + wn + nt * 16 + c) * 40 + g4 * 8];
#pragma unroll
    for (int mt = 0; mt < MT; ++mt)
#pragma unroll
      for (int nt = 0; nt < NT; ++nt)
        acc[mt][nt] = mfma16(af[mt], bf[nt], acc[mt][nt]);
  }

  if (OUTMODE == 0) {
    float* Cf = (float*)Co;
#pragma unroll
    for (int nt = 0; nt < NT; ++nt) {
      int col = n0 + wn + nt * 16 + c;
      float bv = bias ? bias[col] : 0.f;
#pragma unroll
      for (int mt = 0; mt < MT; ++mt)
#pragma unroll
        for (int i = 0; i < 4; ++i)
          Cf[(size_t)(m0 + wm + mt * 16 + g4 * 4 + i) * ldc + col] =
              acc[mt][nt][i] + bv;
    }
  } else if (OUTMODE == 2) {
    u16* C16 = (u16*)Co;
#pragma unroll
    for (int nt = 0; nt < NT; ++nt)
#pragma unroll
      for (int mt = 0; mt < MT; ++mt)
#pragma unroll
        for (int i = 0; i < 4; ++i)
          C16[(size_t)(m0 + wm + mt * 16 + g4 * 4 + i) * ldc + n0 + wn +
              nt * 16 + c] = f2bf(acc[mt][nt][i]);
  } else {
    // OUTMODE 1: requires TM==128, TN==128, WGM==2
    u16* C16 = (u16*)Co;
    u16* Cs = S;  // [64][136] per half
    __syncthreads();
#pragma unroll
    for (int half = 0; half < 2; ++half) {
      if ((wave >> 1) == half) {
#pragma unroll
        for (int nt = 0; nt < NT; ++nt) {
          int col = n0 + wn + nt * 16 + c;
          float bv = bias ? bias[col] : 0.f;
          float sc = (scaleQ && col < 512) ? 0.18033688011112042f : 1.f;
#pragma unroll
          for (int mt = 0; mt < MT; ++mt)
#pragma unroll
            for (int i = 0; i < 4; ++i)
              Cs[(mt * 16 + g4 * 4 + i) * 136 + wn + nt * 16 + c] =
                  f2bf((acc[mt][nt][i] + bv) * sc);
        }
      }
      __syncthreads();
      {
        int row = tid >> 2;
#pragma unroll
        for (int t = 0; t < 4; ++t) {
          int gr = (tid & 3) + t * 4;
          u32x4 v = *(const u32x4*)&Cs[row * 136 + gr * 8];
          *(u32x4*)&C16[(size_t)(m0 + half * 64 + row) * ldc + n0 + gr * 8] = v;
        }
      }
      __syncthreads();
    }
  }
}

// ---------------------------------------------------------------------------
// attn_kernel: flash attention in exp2 domain, no running max.
// 32x32x16 MFMA. S^T = K·Q^T so each lane holds P for its own q-row
// (col=lane&31); P -> bf16 A-frags fully in-register via v_cvt_pk_bf16_f32 +
// permlane32_swap (no P LDS round-trip). K/V LDS double-buffered: 1
// barrier/iter; global prefetch issued right after the barrier, LDS-staged
// after compute. setprio(1) around MFMA clusters. V swizzle &7 both sides
// (write-conflict fix; R1's &3 was 4-way). LDS 70 KB. 32 q/wave, 128 kv/iter.
// ---------------------------------------------------------------------------
__global__ __launch_bounds__(256, 2) void attn_kernel(
    const u16* __restrict__ qkvb, u16* __restrict__ catb) {
  __shared__ __align__(16) u16 Ks[2 * 9216];  // K [kv=128][d=64 +8], x2 buf
  __shared__ __align__(16) u16 Vs[2 * 8704];  // V^T [d=64][kv-pairs swz], x2
  int tid = threadIdx.x;
  int lane = tid & 63, wave = tid >> 6;
  int l31 = lane & 31, hi = lane >> 5;
  int wq = wave * 32;
  int bh = blockIdx.x & 31, qt = blockIdx.x >> 5;
  int bb = bh >> 3, h = bh & 7;
  size_t base = (size_t)bb * 2048 * 1536;

  // Q fragments (B-operand: col=q=l31, k=hi*8+j), 4 chunks of K=16 over d=64
  bf16x8 qf[4];
  {
    int n = qt * 128 + wq + l31;
    const u16* qp = &qkvb[base + (size_t)n * 1536 + h * 64 + hi * 8];
#pragma unroll
    for (int kc = 0; kc < 4; ++kc) qf[kc] = *(const bf16x8*)(qp + kc * 16);
  }

  f32x16 oacc[2];
#pragma unroll
  for (int dt = 0; dt < 2; ++dt)
#pragma unroll
    for (int r = 0; r < 16; ++r) oacc[dt][r] = 0.f;
  float lsum = 0.f;

  su16x8 kpre[4], v0pre[2], v1pre[2];
  int kv_s = tid >> 3, dg_s = tid & 7;  // staging coords (t adds 32 kv rows)

  auto loadKV = [&](int n0k) {
#pragma unroll
    for (int t = 0; t < 4; ++t)
      kpre[t] = *(const su16x8*)&qkvb[base + (size_t)(n0k + kv_s + t * 32) *
                                                1536 +
                                      512 + h * 64 + dg_s * 8];
#pragma unroll
    for (int t = 0; t < 2; ++t) {
      const u16* vg = &qkvb[base + (size_t)(n0k + (kv_s + t * 32) * 2) * 1536 +
                            1024 + h * 64 + dg_s * 8];
      v0pre[t] = *(const su16x8*)vg;
      v1pre[t] = *(const su16x8*)(vg + 1536);
    }
  };

  auto stage = [&](int buf) {
    u16* ksw = Ks + buf * 9216;
    u32* vw = (u32*)(Vs + buf * 8704);
#pragma unroll
    for (int t = 0; t < 4; ++t)
      *(su16x8*)&ksw[(kv_s + t * 32) * 72 + dg_s * 8] = kpre[t];
#pragma unroll
    for (int t = 0; t < 2; ++t) {
      int kvp = kv_s + t * 32;
      int kvg = kvp >> 2, w2 = kvp & 3;
#pragma unroll
      for (int j = 0; j < 8; ++j) {
        int d = dg_s * 8 + j;
        vw[d * 68 + ((kvg ^ (dg_s & 7)) << 2) + w2] =
            (u32)v0pre[t][j] | ((u32)v1pre[t][j] << 16);
      }
    }
  };

  loadKV(0);
  stage(0);
  for (int kb2 = 0; kb2 < 16; ++kb2) {
    __syncthreads();  // staged writes visible; everyone done with other buf
    int cur = kb2 & 1;
    if (kb2 < 15) loadKV((kb2 + 1) * 128);  // global prefetch, consumed at end
    const u16* ksb = Ks + cur * 9216;
    const u16* vsb = Vs + cur * 8704;
#pragma unroll
    for (int kvt = 0; kvt < 4; ++kvt) {
      // ---- S^T tile = K[32 kv] · Q^T  (A=K row=l31, B=Q col=l31) ----
      bf16x8 kf[4];
#pragma unroll
      for (int kc = 0; kc < 4; ++kc)
        kf[kc] =
            *(const bf16x8*)&ksb[(kvt * 32 + l31) * 72 + kc * 16 + hi * 8];
      f32x16 sacc;
#pragma unroll
      for (int r = 0; r < 16; ++r) sacc[r] = 0.f;
      __builtin_amdgcn_s_setprio(1);
#pragma unroll
      for (int kc = 0; kc < 4; ++kc) sacc = mfma32(kf[kc], qf[kc], sacc);
      __builtin_amdgcn_s_setprio(0);
      // ---- P = exp2(S^T): lane owns q=l31, kv t=(r&3)+8*(r>>2)+4*hi ----
      float p[16];
#pragma unroll
      for (int r = 0; r < 16; ++r) p[r] = fexp2(sacc[r]);
      lsum += ((((p[0] + p[1]) + (p[2] + p[3])) +
                ((p[4] + p[5]) + (p[6] + p[7]))) +
               (((p[8] + p[9]) + (p[10] + p[11])) +
                ((p[12] + p[13]) + (p[14] + p[15]))));
      // ---- in-register P -> A-frag bf16 (T12: cvt_pk + permlane32_swap) ----
      u32 a0 = pkbf(p[0], p[1]), b0 = pkbf(p[4], p[5]);
      u32 a1 = pkbf(p[2], p[3]), b1 = pkbf(p[6], p[7]);
      u32 a2 = pkbf(p[8], p[9]), b2 = pkbf(p[12], p[13]);
      u32 a3 = pkbf(p[10], p[11]), b3 = pkbf(p[14], p[15]);
      swap32(a0, b0);
      swap32(a1, b1);
      swap32(a2, b2);
      swap32(a3, b3);
      bf16x8 pf0 = mkfrag(a0, a1, b0, b1);  // kv chunk kvt*32 + [0,16)
      bf16x8 pf1 = mkfrag(a2, a3, b2, b3);  // kv chunk kvt*32 + [16,32)
      // ---- O += P @ V  (B=V col=d=l31, k=kv) ----
      __builtin_amdgcn_s_setprio(1);
#pragma unroll
      for (int kc2 = 0; kc2 < 2; ++kc2) {
        int g = (kvt * 2 + kc2) * 2 + hi;  // 8-kv granule index
#pragma unroll
        for (int dt = 0; dt < 2; ++dt) {
          int d = dt * 32 + l31;
          bf16x8 vf =
              *(const bf16x8*)&vsb[d * 136 + ((g ^ ((d >> 3) & 7)) << 3)];
          oacc[dt] = mfma32(kc2 ? pf1 : pf0, vf, oacc[dt]);
        }
      }
      __builtin_amdgcn_s_setprio(0);
    }
    if (kb2 < 15) stage(cur ^ 1);  // vmcnt wait lands here, after compute
  }
  lsum += __shfl_xor(lsum, 32);
#pragma unroll
  for (int r = 0; r < 16; ++r) {
    int qrow = (r & 3) + 8 * (r >> 2) + 4 * hi;
    float linv = 1.f / __shfl(lsum, qrow);
    size_t n = (size_t)(bb * 2048 + qt * 128 + wq + qrow);
    u16* cp = &catb[n * 768 + h * 64];
    cp[l31] = f2bf(oacc[0][r] * linv);
    cp[32 + l31] = f2bf(oacc[1][r] * linv);
  }
}

// ---------------------------------------------------------------------------
extern "C" void kernel_launch(void* const* d_in, const int* in_sizes, int n_in,
                              void* d_out, int out_size, void* d_ws,
                              size_t ws_size, hipStream_t stream) {
  const float* x = (const float*)d_in[0];
  const float* w_qkv = (const float*)d_in[1];
  const float* b_qkv = (const float*)d_in[2];
  const float* w_in = (const float*)d_in[3];
  const float* b_in = (const float*)d_in[4];
  const float* w_out = (const float*)d_in[5];
  const float* b_out = (const float*)d_in[6];
  const float* w_merge = (const float*)d_in[7];
  const float* b_merge = (const float*)d_in[8];
  const float* w_proj = (const float*)d_in[9];
  const float* b_proj = (const float*)d_in[10];

  char* ws = (char*)d_ws;
  u16* xb = (u16*)(ws + 0);               //  4,194,304 B
  u16* qkvb = (u16*)(ws + 4194304);       // 25,165,824 B
  u16* catb = (u16*)(ws + 29360128);      // 12,582,912 B
  u16* wqkvT = (u16*)(ws + 41943040);     //    786,432 B  [1536][256]
  u16* wptT = (u16*)(ws + 42729472);      //    524,288 B  [512][512]
  u16* wmb = (u16*)(ws + 43253760);       //    524,288 B  [512][512]
  u16* wcombT = (u16*)(ws + 43778048);    //    786,432 B  [512][768]
  float* biasc = (float*)(ws + 44564480); //      2,048 B

  prep_ib_kernel<<<800, 256, 0, stream>>>(w_qkv, w_merge, w_proj, b_merge,
                                          b_proj, wqkvT, wptT, wcombT, wmb,
                                          biasc, x, w_in, b_in, w_out, b_out,
                                          xb, catb);
  // qkv = x @ w_qkv + b_qkv; q scaled by SCALE*log2e in epilogue
  gemm_bt<128, 128, 2, 2, 1><<<dim3(12, 64), 256, 0, stream>>>(
      xb, 256, wqkvT, 256, 256, b_qkv, (void*)qkvb, 1536, 1);
  // wcombT[:, :512] = wptT @ w_merge  (= (w_merge @ w_proj_top)^T)
  gemm_bt<64, 64, 2, 2, 2><<<dim3(8, 8), 256, 0, stream>>>(
      wptT, 512, wmb, 512, 512, nullptr, (void*)wcombT, 768, 0);
  attn_kernel<<<512, 256, 0, stream>>>(qkvb, catb);
  // out = catb @ wcombT^T + biasc  (fp32)
  gemm_bt<128, 64, 4, 1, 0><<<dim3(8, 64), 256, 0, stream>>>(
      catb, 768, wcombT, 768, 768, biasc, d_out, 512, 0);
}

// Round 6
// 175.672 us; speedup vs baseline: 1.9518x; 1.0010x over previous
//
#include <hip/hip_runtime.h>

// ---------------------------------------------------------------------------
// MSAAttention fused pipeline (MI355X / gfx950), bf16 MFMA throughout.
//
// out = concat[softmax(qk^T*s)v @ w_merge + b_merge, ib] @ w_proj + b_proj
// Folded: wcombT holds (w_merge@w_proj_top)^T and w_proj_bot^T — the merge
// GEMM is deleted; biasc = b_merge@w_proj_top + b_proj.
// SCALE*log2e folded into q; softmax in exp2 domain, no max-subtraction.
// attn: R5 per-wave body (32q, in-register P, &7 V swizzle) kept verbatim;
// blocks widened to 512 threads = 8 waves (4 q-quarters x 2 kv-halves) so
// 2 blocks/CU x 8 waves = 4 waves/SIMD (R5 was 2 — ~40% stall-bound).
// Per-CU MFMA/LDS/VALU totals identical to R5; only parallelism changes.
// VGPR audit: persistent ~85 (oacc32+qf16+prefetch32) < 128 cap of
// launch_bounds(512,4) — R3's spill was a 2-q-group live set ~150.
// One-round kv-half O/l combine via LDS at the end.
// ---------------------------------------------------------------------------

typedef unsigned short u16;
typedef unsigned int u32;
typedef __bf16 bf16x8 __attribute__((ext_vector_type(8)));
typedef u16 su16x8 __attribute__((ext_vector_type(8)));
typedef u16 su16x4 __attribute__((ext_vector_type(4)));
typedef u32 u32x4 __attribute__((ext_vector_type(4)));
typedef float f32x4 __attribute__((ext_vector_type(4)));
typedef float f32x16 __attribute__((ext_vector_type(16)));

__device__ __forceinline__ u16 f2bf(float f) {
  union { __bf16 h; u16 u; } v;
  v.h = (__bf16)f;
  return v.u;
}

__device__ __forceinline__ float fexp2(float x) {
#if __has_builtin(__builtin_amdgcn_exp2f)
  return __builtin_amdgcn_exp2f(x);
#else
  return __expf(x * 0.6931471805599453f);
#endif
}

__device__ __forceinline__ f32x4 zero4() {
  f32x4 v = {0.f, 0.f, 0.f, 0.f};
  return v;
}

__device__ __forceinline__ f32x4 mfma16(bf16x8 a, bf16x8 b, f32x4 c) {
  return __builtin_amdgcn_mfma_f32_16x16x32_bf16(a, b, c, 0, 0, 0);
}

__device__ __forceinline__ f32x16 mfma32(bf16x8 a, bf16x8 b, f32x16 c) {
  return __builtin_amdgcn_mfma_f32_32x32x16_bf16(a, b, c, 0, 0, 0);
}

// pack two f32 -> one u32 of two bf16 (lo = a, hi = b)
__device__ __forceinline__ u32 pkbf(float a, float b) {
  u32 r;
  asm("v_cvt_pk_bf16_f32 %0, %1, %2" : "=v"(r) : "v"(a), "v"(b));
  return r;
}

// exchange a's hi-lanes with b's lo-lanes
__device__ __forceinline__ void swap32(u32& a, u32& b) {
  asm("v_permlane32_swap_b32 %0, %1" : "+v"(a), "+v"(b));
}

__device__ __forceinline__ bf16x8 mkfrag(u32 w0, u32 w1, u32 w2, u32 w3) {
  union { u32 u[4]; bf16x8 v; } x;
  x.u[0] = w0; x.u[1] = w1; x.u[2] = w2; x.u[3] = w3;
  return x.v;
}

// ---------------------------------------------------------------------------
// prep_ib_kernel (800 blocks): prep paths (0..287) + ib paths (288..799).
// ---------------------------------------------------------------------------
__global__ __launch_bounds__(256) void prep_ib_kernel(
    const float* __restrict__ w_qkv, const float* __restrict__ w_merge,
    const float* __restrict__ w_proj, const float* __restrict__ b_merge,
    const float* __restrict__ b_proj, u16* __restrict__ wqkvT,
    u16* __restrict__ wptT, u16* __restrict__ wcombT, u16* __restrict__ wmb,
    float* __restrict__ biasc, const float* __restrict__ x,
    const float* __restrict__ w_in, const float* __restrict__ b_in,
    const float* __restrict__ w_out, const float* __restrict__ b_out,
    u16* __restrict__ xb, u16* __restrict__ catb) {
  __shared__ __align__(16) char smem[35456];
  int blk = blockIdx.x, tid = threadIdx.x;
  if (blk < 192) {
    const float* src;
    int lsrc, ldd, r0, c0;
    u16* dst;
    if (blk < 96) {
      src = w_qkv; lsrc = 1536; dst = wqkvT; ldd = 256;
      r0 = (blk & 3) * 64; c0 = (blk >> 2) * 64;
    } else if (blk < 160) {
      int b2 = blk - 96;
      src = w_proj; lsrc = 512; dst = wptT; ldd = 512;
      r0 = (b2 & 7) * 64; c0 = (b2 >> 3) * 64;
    } else {
      int b2 = blk - 160;
      src = w_proj + 512 * 512; lsrc = 512; dst = wcombT + 512; ldd = 768;
      r0 = (b2 & 3) * 64; c0 = (b2 >> 2) * 64;
    }
    u16* Ts = (u16*)smem;  // [64][68]
    int rr = tid >> 4, cc4 = (tid & 15) * 4;
#pragma unroll
    for (int rep = 0; rep < 4; ++rep) {
      int r = rr + rep * 16;
      float4 v = *(const float4*)&src[(size_t)(r0 + r) * lsrc + c0 + cc4];
      su16x4 pk = {f2bf(v.x), f2bf(v.y), f2bf(v.z), f2bf(v.w)};
      *(su16x4*)&Ts[r * 68 + cc4] = pk;
    }
    __syncthreads();
    int c = tid & 63, seg = tid >> 6;
    u16 tmp[16];
#pragma unroll
    for (int k = 0; k < 16; ++k) tmp[k] = Ts[(seg * 16 + k) * 68 + c];
    *(su16x8*)&dst[(size_t)(c0 + c) * ldd + r0 + seg * 16] = *(su16x8*)tmp;
    *(su16x8*)&dst[(size_t)(c0 + c) * ldd + r0 + seg * 16 + 8] =
        *(su16x8*)(tmp + 8);
  } else if (blk < 256) {
    int b2 = blk - 192;
#pragma unroll
    for (int rep = 0; rep < 4; ++rep) {
      int i = b2 * 4096 + rep * 1024 + tid * 4;
      float4 v = *(const float4*)&w_merge[i];
      su16x4 pk = {f2bf(v.x), f2bf(v.y), f2bf(v.z), f2bf(v.w)};
      *(su16x4*)&wmb[i] = pk;
    }
  } else if (blk < 288) {
    int col0 = (blk - 256) * 16;
    float(*red)[17] = (float(*)[17])smem;
    int kr = tid >> 4, cc = tid & 15;
    float s = 0.f;
#pragma unroll 4
    for (int j = 0; j < 32; ++j) {
      int k = kr + j * 16;
      s += b_merge[k] * w_proj[(size_t)k * 512 + col0 + cc];
    }
    red[kr][cc] = s;
    __syncthreads();
    if (kr == 0) {
      float a = b_proj[col0 + cc];
#pragma unroll
      for (int t = 0; t < 16; ++t) a += red[t][cc];
      biasc[col0 + cc] = a;
    }
  } else {
    int ib = blk - 288;
    float* wi = (float*)smem;            // 256
    float* wo = (float*)(smem + 1024);   // 256
    float* bi = (float*)(smem + 2048);   // 16
    float* bo = (float*)(smem + 2112);   // 16
    float(*xs)[260] = (float(*)[260])(smem + 2176);
    float(*hs)[260] = (float(*)[260])(smem + 18816);
    wi[tid] = w_in[tid];
    wo[tid] = w_out[tid];
    if (tid < 16) { bi[tid] = b_in[tid]; bo[tid] = b_out[tid]; }
    size_t blkoff = (size_t)ib * 4096;
#pragma unroll
    for (int i = 0; i < 4; ++i) {
      int f = (tid + i * 256) * 4;
      float4 v = *(const float4*)&x[blkoff + f];
      int tok = f >> 8, p = f & 255;
      *(float4*)&xs[tok][p] = v;
      su16x4 pk = {f2bf(v.x), f2bf(v.y), f2bf(v.z), f2bf(v.w)};
      *(su16x4*)&xb[blkoff + f] = pk;
    }
    __syncthreads();
    int t = tid >> 4, p2 = tid & 15;
#pragma unroll
    for (int p1 = 0; p1 < 16; ++p1) {
      float a = bi[p2];
#pragma unroll
      for (int k = 0; k < 16; ++k) a += xs[t][p1 * 16 + k] * wi[k * 16 + p2];
      hs[t][p1 * 16 + p2] = a / (1.f + __expf(-a));
    }
    __syncthreads();
    size_t tok = (size_t)ib * 16 + t;
#pragma unroll
    for (int p1 = 0; p1 < 16; ++p1) {
      float o = bo[p2];
#pragma unroll
      for (int j = 0; j < 16; ++j) o += hs[t][p1 * 16 + j] * wo[j * 16 + p2];
      catb[tok * 768 + 512 + p1 * 16 + p2] = f2bf(o);
    }
  }
}

// ---------------------------------------------------------------------------
// gemm_bt: C[TM-tile][TN-tile] = A[m][k] @ BT[n][k]^T  (both row-major, k-inner)
// OUTMODE 0: f32 out (+bias). 1: bf16 out via LDS-staged b128 stores (+bias,
// scaleQ multiplies cols<512 by SCALE*log2e). 2: bf16 scatter (small tiles).
// ---------------------------------------------------------------------------
template <int TM, int TN, int WGM, int WGN, int OUTMODE>
__global__ __launch_bounds__(256) void gemm_bt(
    const u16* __restrict__ A, int lda, const u16* __restrict__ BT, int ldb,
    int kcount, const float* __restrict__ bias, void* __restrict__ Co, int ldc,
    int scaleQ) {
  constexpr int NROWS = TM + TN;
  constexpr int NLD = NROWS / 64;
  constexpr int MT = TM / WGM / 16;
  constexpr int NT = TN / WGN / 16;
  __shared__ __align__(16) u16 S[NROWS * 40];
  int tid = threadIdx.x;
  int lane = tid & 63, wave = tid >> 6;
  int c = lane & 15, g4 = lane >> 4;
  int m0 = blockIdx.y * TM, n0 = blockIdx.x * TN;
  int wm = (wave / WGN) * (TM / WGM), wn = (wave % WGN) * (TN / WGN);
  f32x4 acc[MT][NT];
#pragma unroll
  for (int a = 0; a < MT; ++a)
#pragma unroll
    for (int b = 0; b < NT; ++b) acc[a][b] = zero4();

  su16x8 pre[NLD];
#pragma unroll
  for (int t = 0; t < NLD; ++t) {
    int gsl = t * 256 + tid;
    int row = gsl >> 2, kg = gsl & 3;
    const u16* p = row < TM ? &A[(size_t)(m0 + row) * lda + kg * 8]
                            : &BT[(size_t)(n0 + row - TM) * ldb + kg * 8];
    pre[t] = *(const su16x8*)p;
  }

  for (int kb = 0; kb < kcount; kb += 32) {
    __syncthreads();
#pragma unroll
    for (int t = 0; t < NLD; ++t) {
      int gsl = t * 256 + tid;
      int row = gsl >> 2, kg = gsl & 3;
      *(su16x8*)&S[row * 40 + kg * 8] = pre[t];
    }
    __syncthreads();
    if (kb + 32 < kcount) {
#pragma unroll
      for (int t = 0; t < NLD; ++t) {
        int gsl = t * 256 + tid;
        int row = gsl >> 2, kg = gsl & 3;
        const u16* p =
            row < TM ? &A[(size_t)(m0 + row) * lda + kb + 32 + kg * 8]
                     : &BT[(size_t)(n0 + row - TM) * ldb + kb + 32 + kg * 8];
        pre[t] = *(const su16x8*)p;
      }
    }
    bf16x8 af[MT], bf[NT];
#pragma unroll
    for (int mt = 0; mt < MT; ++mt)
      af[mt] = *(const bf16x8*)&S[(wm + mt * 16 + c) * 40 + g4 * 8];
#pragma unroll
    for (int nt = 0; nt < NT; ++nt)
      bf[nt] = *(const bf16x8*)&S[(TM + wn + nt * 16 + c) * 40 + g4 * 8];
#pragma unroll
    for (int mt = 0; mt < MT; ++mt)
#pragma unroll
      for (int nt = 0; nt < NT; ++nt)
        acc[mt][nt] = mfma16(af[mt], bf[nt], acc[mt][nt]);
  }

  if (OUTMODE == 0) {
    float* Cf = (float*)Co;
#pragma unroll
    for (int nt = 0; nt < NT; ++nt) {
      int col = n0 + wn + nt * 16 + c;
      float bv = bias ? bias[col] : 0.f;
#pragma unroll
      for (int mt = 0; mt < MT; ++mt)
#pragma unroll
        for (int i = 0; i < 4; ++i)
          Cf[(size_t)(m0 + wm + mt * 16 + g4 * 4 + i) * ldc + col] =
              acc[mt][nt][i] + bv;
    }
  } else if (OUTMODE == 2) {
    u16* C16 = (u16*)Co;
#pragma unroll
    for (int nt = 0; nt < NT; ++nt)
#pragma unroll
      for (int mt = 0; mt < MT; ++mt)
#pragma unroll
        for (int i = 0; i < 4; ++i)
          C16[(size_t)(m0 + wm + mt * 16 + g4 * 4 + i) * ldc + n0 + wn +
              nt * 16 + c] = f2bf(acc[mt][nt][i]);
  } else {
    // OUTMODE 1: requires TM==128, TN==128, WGM==2
    u16* C16 = (u16*)Co;
    u16* Cs = S;  // [64][136] per half
    __syncthreads();
#pragma unroll
    for (int half = 0; half < 2; ++half) {
      if ((wave >> 1) == half) {
#pragma unroll
        for (int nt = 0; nt < NT; ++nt) {
          int col = n0 + wn + nt * 16 + c;
          float bv = bias ? bias[col] : 0.f;
          float sc = (scaleQ && col < 512) ? 0.18033688011112042f : 1.f;
#pragma unroll
          for (int mt = 0; mt < MT; ++mt)
#pragma unroll
            for (int i = 0; i < 4; ++i)
              Cs[(mt * 16 + g4 * 4 + i) * 136 + wn + nt * 16 + c] =
                  f2bf((acc[mt][nt][i] + bv) * sc);
        }
      }
      __syncthreads();
      {
        int row = tid >> 2;
#pragma unroll
        for (int t = 0; t < 4; ++t) {
          int gr = (tid & 3) + t * 4;
          u32x4 v = *(const u32x4*)&Cs[row * 136 + gr * 8];
          *(u32x4*)&C16[(size_t)(m0 + half * 64 + row) * ldc + n0 + gr * 8] = v;
        }
      }
      __syncthreads();
    }
  }
}

// ---------------------------------------------------------------------------
// attn_kernel: flash attention in exp2 domain, no running max.
// 512 threads = 8 waves = (q-quarter qh x kv-half kh) over a 128q block.
// KVBLK=128 double-buffered (LDS 71.7 KB) -> 2 blocks/CU = 4 waves/SIMD.
// Per wave-iter: own kv-half = 2 kvt phases (R5 body per phase, verbatim).
// 32x32x16 MFMA, swapped QK^T, P in-register (cvt_pk + permlane32_swap).
// 1 barrier/iter; one-round kv-half O/l combine via LDS at the end.
// ---------------------------------------------------------------------------
__global__ __launch_bounds__(512, 4) void attn_kernel(
    const u16* __restrict__ qkvb, u16* __restrict__ catb) {
  __shared__ __align__(16) u16 Ks[2 * 9216];  // K [kv=128][d=64 +8], x2 buf
  __shared__ __align__(16) u16 Vs[2 * 8704];  // V^T [d=64][kv-pairs swz], x2
  int tid = threadIdx.x;
  int lane = tid & 63, wave = tid >> 6;
  int l31 = lane & 31, hi = lane >> 5;
  int qh = wave >> 1, kh = wave & 1;  // q-quarter (32 q), kv-half (64 kv)
  int wq = qh * 32;
  int bh = blockIdx.x & 31, qt = blockIdx.x >> 5;
  int bb = bh >> 3, h = bh & 7;
  size_t base = (size_t)bb * 2048 * 1536;

  // Q fragments (B-operand: col=q=l31, k=hi*8+j), 4 chunks of K=16 over d=64
  bf16x8 qf[4];
  {
    int n = qt * 128 + wq + l31;
    const u16* qp = &qkvb[base + (size_t)n * 1536 + h * 64 + hi * 8];
#pragma unroll
    for (int kc = 0; kc < 4; ++kc) qf[kc] = *(const bf16x8*)(qp + kc * 16);
  }

  f32x16 oacc[2];
#pragma unroll
  for (int dt = 0; dt < 2; ++dt)
#pragma unroll
    for (int r = 0; r < 16; ++r) oacc[dt][r] = 0.f;
  float lsum = 0.f;

  su16x8 kpre[2], v0pre, v1pre;
  int kv_s = tid >> 3, dg_s = tid & 7;  // staging coords (512 threads)

  auto loadKV = [&](int n0k) {
#pragma unroll
    for (int t = 0; t < 2; ++t)
      kpre[t] = *(const su16x8*)&qkvb[base + (size_t)(n0k + kv_s + t * 64) *
                                                1536 +
                                      512 + h * 64 + dg_s * 8];
    {
      const u16* vg = &qkvb[base + (size_t)(n0k + kv_s * 2) * 1536 + 1024 +
                            h * 64 + dg_s * 8];
      v0pre = *(const su16x8*)vg;
      v1pre = *(const su16x8*)(vg + 1536);
    }
  };

  auto stage = [&](int buf) {
    u16* ksw = Ks + buf * 9216;
    u32* vw = (u32*)(Vs + buf * 8704);
#pragma unroll
    for (int t = 0; t < 2; ++t)
      *(su16x8*)&ksw[(kv_s + t * 64) * 72 + dg_s * 8] = kpre[t];
    {
      int kvg = kv_s >> 2, w2 = kv_s & 3;  // pair granule in [0,16)
#pragma unroll
      for (int j = 0; j < 8; ++j) {
        int d = dg_s * 8 + j;
        vw[d * 68 + ((kvg ^ (dg_s & 7)) << 2) + w2] =
            (u32)v0pre[j] | ((u32)v1pre[j] << 16);
      }
    }
  };

  loadKV(0);
  stage(0);
  for (int kb2 = 0; kb2 < 16; ++kb2) {
    __syncthreads();  // staged writes visible; everyone done with other buf
    int cur = kb2 & 1;
    if (kb2 < 15) loadKV((kb2 + 1) * 128);  // global prefetch, consumed at end
    const u16* ksb = Ks + cur * 9216;
    const u16* vsb = Vs + cur * 8704;
#pragma unroll
    for (int kvt = 0; kvt < 2; ++kvt) {
      // ---- S^T tile = K[32 kv of own half] · Q^T ----
      bf16x8 kf[4];
#pragma unroll
      for (int kc = 0; kc < 4; ++kc)
        kf[kc] = *(const bf16x8*)&ksb[(kh * 64 + kvt * 32 + l31) * 72 +
                                      kc * 16 + hi * 8];
      f32x16 sacc;
#pragma unroll
      for (int r = 0; r < 16; ++r) sacc[r] = 0.f;
      __builtin_amdgcn_s_setprio(1);
#pragma unroll
      for (int kc = 0; kc < 4; ++kc) sacc = mfma32(kf[kc], qf[kc], sacc);
      __builtin_amdgcn_s_setprio(0);
      // ---- P = exp2(S^T): lane owns q=l31, kv row=(r&3)+8*(r>>2)+4*hi ----
      float p[16];
#pragma unroll
      for (int r = 0; r < 16; ++r) p[r] = fexp2(sacc[r]);
      lsum += ((((p[0] + p[1]) + (p[2] + p[3])) +
                ((p[4] + p[5]) + (p[6] + p[7]))) +
               (((p[8] + p[9]) + (p[10] + p[11])) +
                ((p[12] + p[13]) + (p[14] + p[15]))));
      // ---- in-register P -> A-frag bf16 (cvt_pk + permlane32_swap) ----
      u32 a0 = pkbf(p[0], p[1]), b0 = pkbf(p[4], p[5]);
      u32 a1 = pkbf(p[2], p[3]), b1 = pkbf(p[6], p[7]);
      u32 a2 = pkbf(p[8], p[9]), b2 = pkbf(p[12], p[13]);
      u32 a3 = pkbf(p[10], p[11]), b3 = pkbf(p[14], p[15]);
      swap32(a0, b0);
      swap32(a1, b1);
      swap32(a2, b2);
      swap32(a3, b3);
      bf16x8 pf0 = mkfrag(a0, a1, b0, b1);  // kv [kvt*32, +16) of own half
      bf16x8 pf1 = mkfrag(a2, a3, b2, b3);  // kv [kvt*32+16, +32)
      // ---- O += P @ V ----
      __builtin_amdgcn_s_setprio(1);
#pragma unroll
      for (int kc2 = 0; kc2 < 2; ++kc2) {
        int g = kh * 8 + kvt * 4 + kc2 * 2 + hi;  // 8-kv granule in [0,16)
#pragma unroll
        for (int dt = 0; dt < 2; ++dt) {
          int d = dt * 32 + l31;
          bf16x8 vf =
              *(const bf16x8*)&vsb[d * 136 + ((g ^ ((d >> 3) & 7)) << 3)];
          oacc[dt] = mfma32(kc2 ? pf1 : pf0, vf, oacc[dt]);
        }
      }
      __builtin_amdgcn_s_setprio(0);
    }
    if (kb2 < 15) stage(cur ^ 1);  // vmcnt wait lands here, after compute
  }
  lsum += __shfl_xor(lsum, 32);

  // ---- cross-wave kv-half combine (reuse LDS; once per block) ----
  __syncthreads();
  float* Of = (float*)Ks;  // [4 qh][32 q][68] f32 = 34,816 B
  float* Lf = (float*)Vs;  // [4 qh][32] f32
  if (kh == 1) {
#pragma unroll
    for (int dt = 0; dt < 2; ++dt)
#pragma unroll
      for (int r = 0; r < 16; ++r) {
        int qrow = (r & 3) + 8 * (r >> 2) + 4 * hi;
        Of[(qh * 32 + qrow) * 68 + dt * 32 + l31] = oacc[dt][r];
      }
    if (hi == 0) Lf[qh * 32 + l31] = lsum;
  }
  __syncthreads();
  if (kh == 0) {
    float lt = lsum + Lf[qh * 32 + l31];
#pragma unroll
    for (int r = 0; r < 16; ++r) {
      int qrow = (r & 3) + 8 * (r >> 2) + 4 * hi;
      float linv = 1.f / __shfl(lt, qrow);
      float o0 = oacc[0][r] + Of[(qh * 32 + qrow) * 68 + l31];
      float o1 = oacc[1][r] + Of[(qh * 32 + qrow) * 68 + 32 + l31];
      size_t n = (size_t)(bb * 2048 + qt * 128 + wq + qrow);
      u16* cp = &catb[n * 768 + h * 64];
      cp[l31] = f2bf(o0 * linv);
      cp[32 + l31] = f2bf(o1 * linv);
    }
  }
}

// ---------------------------------------------------------------------------
extern "C" void kernel_launch(void* const* d_in, const int* in_sizes, int n_in,
                              void* d_out, int out_size, void* d_ws,
                              size_t ws_size, hipStream_t stream) {
  const float* x = (const float*)d_in[0];
  const float* w_qkv = (const float*)d_in[1];
  const float* b_qkv = (const float*)d_in[2];
  const float* w_in = (const float*)d_in[3];
  const float* b_in = (const float*)d_in[4];
  const float* w_out = (const float*)d_in[5];
  const float* b_out = (const float*)d_in[6];
  const float* w_merge = (const float*)d_in[7];
  const float* b_merge = (const float*)d_in[8];
  const float* w_proj = (const float*)d_in[9];
  const float* b_proj = (const float*)d_in[10];

  char* ws = (char*)d_ws;
  u16* xb = (u16*)(ws + 0);               //  4,194,304 B
  u16* qkvb = (u16*)(ws + 4194304);       // 25,165,824 B
  u16* catb = (u16*)(ws + 29360128);      // 12,582,912 B
  u16* wqkvT = (u16*)(ws + 41943040);     //    786,432 B  [1536][256]
  u16* wptT = (u16*)(ws + 42729472);      //    524,288 B  [512][512]
  u16* wmb = (u16*)(ws + 43253760);       //    524,288 B  [512][512]
  u16* wcombT = (u16*)(ws + 43778048);    //    786,432 B  [512][768]
  float* biasc = (float*)(ws + 44564480); //      2,048 B

  prep_ib_kernel<<<800, 256, 0, stream>>>(w_qkv, w_merge, w_proj, b_merge,
                                          b_proj, wqkvT, wptT, wcombT, wmb,
                                          biasc, x, w_in, b_in, w_out, b_out,
                                          xb, catb);
  // qkv = x @ w_qkv + b_qkv; q scaled by SCALE*log2e in epilogue
  gemm_bt<128, 128, 2, 2, 1><<<dim3(12, 64), 256, 0, stream>>>(
      xb, 256, wqkvT, 256, 256, b_qkv, (void*)qkvb, 1536, 1);
  // wcombT[:, :512] = wptT @ w_merge  (= (w_merge @ w_proj_top)^T)
  gemm_bt<64, 64, 2, 2, 2><<<dim3(8, 8), 256, 0, stream>>>(
      wptT, 512, wmb, 512, 512, nullptr, (void*)wcombT, 768, 0);
  attn_kernel<<<512, 512, 0, stream>>>(qkvb, catb);
  // out = catb @ wcombT^T + biasc  (fp32)
  gemm_bt<128, 64, 4, 1, 0><<<dim3(8, 64), 256, 0, stream>>>(
      catb, 768, wcombT, 768, 768, biasc, d_out, 512, 0);
}